// Round 10
// baseline (574.057 us; speedup 1.0000x reference)
//
#include <hip/hip_runtime.h>
#include <hip/hip_bf16.h>
#include <math.h>

// Problem constants
#define T_     1024
#define DIM_   2048
#define H_     16
#define QLR_   1024
#define KVLR_  512
#define NOPE_  128
#define ROPE_  64
#define VD_    128
#define QKD_   192   // NOPE+ROPE
#define IH_    16
#define ID_    128
#define TOPK_  256
#define CKV_   576   // KVLR + ROPE

#define SCALE_W    0.022097086912079608f   // IH^-0.5 * ID^-0.5
#define SCALE_LOG  0.07216878364870323f    // QKD^-0.5

typedef short bfrag __attribute__((ext_vector_type(8)));   // 8 bf16 = 4 VGPRs
typedef float ffrag __attribute__((ext_vector_type(4)));   // 4 fp32 acc

__device__ __forceinline__ unsigned short f2bf(float f) {
    union { __hip_bfloat16 h; unsigned short u; } c; c.h = __float2bfloat16(f); return c.u;
}
__device__ __forceinline__ float bf2f(unsigned short u) {
    union { unsigned short u; __hip_bfloat16 h; } c; c.u = u; return __bfloat162float(c.h);
}

// ---------------------------------------------------------------------------
// Multi-segment cast: N independent fp32->bf16 (hi or hi+lo) casts, 1 launch.
// ---------------------------------------------------------------------------
struct CastSeg { const float* src; unsigned short* hi; unsigned short* lo; };
struct CastDesc { CastSeg seg[6]; int bstart[7]; int nseg; };

__global__ __launch_bounds__(256) void castm_k(CastDesc d)
{
    int b = blockIdx.x, s = 0;
    #pragma unroll
    for (int i = 1; i < 6; ++i) if (i < d.nseg && b >= d.bstart[i]) s = i;
    long base = ((long)(b - d.bstart[s]) * 256 + threadIdx.x) * 4;
    float4 v = *(const float4*)(d.seg[s].src + base);
    ushort4 h4;
    h4.x = f2bf(v.x); h4.y = f2bf(v.y); h4.z = f2bf(v.z); h4.w = f2bf(v.w);
    *(ushort4*)(d.seg[s].hi + base) = h4;
    if (d.seg[s].lo) {
        ushort4 l4;
        l4.x = f2bf(v.x - bf2f(h4.x));
        l4.y = f2bf(v.y - bf2f(h4.y));
        l4.z = f2bf(v.z - bf2f(h4.z));
        l4.w = f2bf(v.w - bf2f(h4.w));
        *(ushort4*)(d.seg[s].lo + base) = l4;
    }
}

// ---------------------------------------------------------------------------
// Fused rstd + both qr casts: one block per token row (1024 cols).
// ---------------------------------------------------------------------------
__global__ __launch_bounds__(256) void qrnorm_k(const float* __restrict__ qr,
    const float* __restrict__ iqw, const float* __restrict__ qw,
    unsigned short* __restrict__ qriq_hi, unsigned short* __restrict__ qriq_lo,
    unsigned short* __restrict__ qrq_hi)
{
    int t = blockIdx.x, tid = threadIdx.x;
    long base = (long)t * QLR_ + tid * 4;
    float4 v = *(const float4*)(qr + base);
    __shared__ float red[256];
    red[tid] = v.x * v.x + v.y * v.y + v.z * v.z + v.w * v.w;
    __syncthreads();
    for (int off = 128; off; off >>= 1) { if (tid < off) red[tid] += red[tid + off]; __syncthreads(); }
    float r = rsqrtf(red[0] / (float)QLR_ + 1e-6f);
    int col = tid * 4;
    float4 wi = *(const float4*)(iqw + col);
    float4 wq = *(const float4*)(qw + col);
    float s[4] = {v.x, v.y, v.z, v.w};
    float wiv[4] = {wi.x, wi.y, wi.z, wi.w};
    float wqv[4] = {wq.x, wq.y, wq.z, wq.w};
    ushort4 h4, l4, g4;
    unsigned short* hp = (unsigned short*)&h4;
    unsigned short* lp = (unsigned short*)&l4;
    unsigned short* gp = (unsigned short*)&g4;
    #pragma unroll
    for (int i = 0; i < 4; ++i) {
        float ai = s[i] * wiv[i] * r;
        float aq = s[i] * wqv[i] * r;
        hp[i] = f2bf(ai);
        lp[i] = f2bf(ai - bf2f(hp[i]));
        gp[i] = f2bf(aq);
    }
    *(ushort4*)(qriq_hi + base) = h4;
    *(ushort4*)(qriq_lo + base) = l4;
    *(ushort4*)(qrq_hi + base) = g4;
}

// ---------------------------------------------------------------------------
// MFMA bf16 NT GEMM, 128x128 tile (batched q_nope_proj, K=128). BK=32.
// ---------------------------------------------------------------------------
__global__ __launch_bounds__(256) void gemm_bt_mfma_k(
    const unsigned short* __restrict__ A, const unsigned short* __restrict__ B,
    void* __restrict__ Cv, long sA, long sB, long sC,
    int lda, int ldb, int ldc, int N, int K, int obf)
{
    A += (long)blockIdx.z * sA;
    B += (long)blockIdx.z * sB;
    __shared__ unsigned short As[128 * 40];
    __shared__ unsigned short Bs[128 * 40];
    const int tid = threadIdx.x;
    const int bm = blockIdx.y * 128, bn = blockIdx.x * 128;
    const int wave = tid >> 6, lane = tid & 63;
    const int wm = (wave >> 1) * 64, wn = (wave & 1) * 64;
    const int lm = lane & 15, quad = lane >> 4;

    ffrag acc[4][4];
    #pragma unroll
    for (int mi = 0; mi < 4; ++mi)
        #pragma unroll
        for (int ni = 0; ni < 4; ++ni)
            #pragma unroll
            for (int r = 0; r < 4; ++r) acc[mi][ni][r] = 0.f;

    const int srow = tid >> 1, shalf = tid & 1;
    const long aoff = (long)(bm + srow) * lda + shalf * 16;
    int brow = bn + srow; if (brow > N - 1) brow = N - 1;
    const long boff = (long)brow * ldb + shalf * 16;
    unsigned short* la = As + srow * 40 + shalf * 16;
    unsigned short* lb = Bs + srow * 40 + shalf * 16;

    uint4 va0 = *(const uint4*)(A + aoff);
    uint4 va1 = *(const uint4*)(A + aoff + 8);
    uint4 vb0 = *(const uint4*)(B + boff);
    uint4 vb1 = *(const uint4*)(B + boff + 8);

    for (int k0 = 0; k0 < K; k0 += 32) {
        __syncthreads();
        *(uint4*)la = va0; *(uint4*)(la + 8) = va1;
        *(uint4*)lb = vb0; *(uint4*)(lb + 8) = vb1;
        __syncthreads();
        if (k0 + 32 < K) {
            va0 = *(const uint4*)(A + aoff + k0 + 32);
            va1 = *(const uint4*)(A + aoff + k0 + 40);
            vb0 = *(const uint4*)(B + boff + k0 + 32);
            vb1 = *(const uint4*)(B + boff + k0 + 40);
        }
        bfrag af[4], bf[4];
        #pragma unroll
        for (int mi = 0; mi < 4; ++mi)
            af[mi] = *(const bfrag*)(As + (wm + mi * 16 + lm) * 40 + quad * 8);
        #pragma unroll
        for (int ni = 0; ni < 4; ++ni)
            bf[ni] = *(const bfrag*)(Bs + (wn + ni * 16 + lm) * 40 + quad * 8);
        #pragma unroll
        for (int mi = 0; mi < 4; ++mi)
            #pragma unroll
            for (int ni = 0; ni < 4; ++ni)
                acc[mi][ni] = __builtin_amdgcn_mfma_f32_16x16x32_bf16(
                    af[mi], bf[ni], acc[mi][ni], 0, 0, 0);
    }

    #pragma unroll
    for (int mi = 0; mi < 4; ++mi)
        #pragma unroll
        for (int ni = 0; ni < 4; ++ni) {
            int n = bn + wn + ni * 16 + lm;
            if (n < N) {
                int mb = bm + wm + mi * 16 + quad * 4;
                if (obf) {
                    unsigned short* C = (unsigned short*)Cv + (long)blockIdx.z * sC;
                    #pragma unroll
                    for (int r = 0; r < 4; ++r)
                        C[(long)(mb + r) * ldc + n] = f2bf(acc[mi][ni][r]);
                } else {
                    float* C = (float*)Cv + (long)blockIdx.z * sC;
                    #pragma unroll
                    for (int r = 0; r < 4; ++r)
                        C[(long)(mb + r) * ldc + n] = acc[mi][ni][r];
                }
            }
        }
}

// ---------------------------------------------------------------------------
// Multi-segment fused kernel. GEMM path: 128x128 tile, BK=32, depth-1
// register prefetch (the proven gemm_bt_mfma_k structure) extended with a
// bf16x3 (hi/lo) variant. 2x arithmetic intensity vs the old 64x64 tile
// (24 vs 12 FLOP per staged byte) -- the 64x64 structure measured at its
// ~350TF structural ceiling. Accumulation per C element is sequential k
// 32-chunks in hh,hl,lh order = bit-identical to rounds 5-8.
// modes: 0=gemm128 bf16, 1=gemm128 bf16x3, 2=cast f32->bf16(hi[,lo]),
//        3=wtok, 4=tcast(wkv_b->wkT), 5=qpe
// ---------------------------------------------------------------------------
struct GSeg {
    const void* A; const void* Al; const void* B; const void* Bl;
    void* C; void* C2;
    long sA, sB, sC;
    int lda, ldb, ldc, N, K, bnx, bmx, mode, obf;
};
struct GDesc { GSeg seg[4]; int bstart[5]; int nseg; };

__global__ __launch_bounds__(256) void mgemm_k(GDesc d)
{
    __shared__ unsigned short SM[20480];   // 40.96 KB
    unsigned short* As  = SM;              // [128][40]
    unsigned short* Bs  = SM + 5120;       // [128][40]
    unsigned short* Als = SM + 10240;      // [128][40] (bf16x3 only)
    unsigned short* Bls = SM + 15360;      // [128][40] (bf16x3 only)
    const int tid = threadIdx.x;
    const int b = blockIdx.x;
    int s = 0;
    #pragma unroll
    for (int i = 1; i < 4; ++i) if (i < d.nseg && b >= d.bstart[i]) s = i;
    const int rel = b - d.bstart[s];
    const int mode = d.seg[s].mode;

    if (mode == 2) {   // fp32 -> bf16 cast (hi [, lo])
        const float* src = (const float*)d.seg[s].A;
        unsigned short* hi = (unsigned short*)d.seg[s].C;
        unsigned short* lo = (unsigned short*)d.seg[s].C2;
        long base = ((long)rel * 256 + tid) * 4;
        float4 v = *(const float4*)(src + base);
        ushort4 h4;
        h4.x = f2bf(v.x); h4.y = f2bf(v.y); h4.z = f2bf(v.z); h4.w = f2bf(v.w);
        *(ushort4*)(hi + base) = h4;
        if (lo) {
            ushort4 l4;
            l4.x = f2bf(v.x - bf2f(h4.x));
            l4.y = f2bf(v.y - bf2f(h4.y));
            l4.z = f2bf(v.z - bf2f(h4.z));
            l4.w = f2bf(v.w - bf2f(h4.w));
            *(ushort4*)(lo + base) = l4;
        }
        return;
    }
    if (mode == 3) {   // wtok
        const float* x = (const float*)d.seg[s].A;
        const float* wproj = (const float*)d.seg[s].B;
        float* wt = (float*)d.seg[s].C;
        float* xs = (float*)SM;            // 2048 floats = 8KB
        int t = rel;
        for (int c = tid; c < DIM_; c += 256) xs[c] = x[(long)t * DIM_ + c];
        __syncthreads();
        int wave = tid >> 6, lane = tid & 63;
        #pragma unroll
        for (int i = 0; i < 4; ++i) {
            int h = wave * 4 + i;
            float sum = 0.f;
            for (int c = lane; c < DIM_; c += 64) sum += xs[c] * wproj[(long)h * DIM_ + c];
            for (int off = 32; off; off >>= 1) sum += __shfl_xor(sum, off, 64);
            if (lane == 0) wt[(long)t * IH_ + h] = sum * SCALE_W;
        }
        return;
    }
    if (mode == 4) {   // tcast: wkT[h][c][d] = bf16(wkv_b[(h*256+d)*512+c])
        const float* in = (const float*)d.seg[s].A;
        unsigned short* out = (unsigned short*)d.seg[s].C;
        int h = rel >> 6, c0 = (rel & 15) * 32, d0 = ((rel >> 4) & 3) * 32;
        float (*tt)[33] = (float(*)[33])(void*)SM;   // 4224B
        int tx = tid & 31, ty = tid >> 5;
        #pragma unroll
        for (int i = 0; i < 4; ++i)
            tt[ty + i * 8][tx] = in[(long)(h * 256 + d0 + ty + i * 8) * 512 + c0 + tx];
        __syncthreads();
        #pragma unroll
        for (int i = 0; i < 4; ++i)
            out[((long)h * 512 + c0 + ty + i * 8) * 128 + d0 + tx] = f2bf(tt[tx][ty + i * 8]);
        return;
    }
    if (mode == 5) {   // qpe: 8 rows per block, 32 lanes per row
        const float* q = (const float*)d.seg[s].A;
        const float* cosb = (const float*)d.seg[s].B;
        const float* sinb = (const float*)d.seg[s].Bl;
        unsigned short* qk = (unsigned short*)d.seg[s].C;
        int row = rel * 8 + (tid >> 5);
        int i = tid & 31;
        int t = row / H_;
        const float* qp = q + (long)row * QKD_ + NOPE_;
        float x1 = qp[i], x2 = qp[i + 32];
        float c = cosb[t * 32 + i], sn = sinb[t * 32 + i];
        unsigned short* o = qk + (long)row * CKV_ + 512;
        o[i]      = f2bf(x1 * c - x2 * sn);
        o[i + 32] = f2bf(x1 * sn + x2 * c);
        return;
    }

    // ---- GEMM modes 0 / 1: 128x128 tile, BK=32, depth-1 prefetch ----
    const GSeg g = d.seg[s];
    const bool three = (mode == 1);
    const int per = g.bnx * g.bmx;
    const int z = rel / per;
    const int r2 = rel - z * per;
    const int bm = (r2 / g.bnx) * 128, bn = (r2 % g.bnx) * 128;
    const unsigned short* A   = (const unsigned short*)g.A + (long)z * g.sA;
    const unsigned short* B   = (const unsigned short*)g.B + (long)z * g.sB;
    const unsigned short* Alp = (const unsigned short*)g.Al;
    const unsigned short* Blp = (const unsigned short*)g.Bl;

    const int wave = tid >> 6, lane = tid & 63;
    const int wm = (wave >> 1) * 64, wn = (wave & 1) * 64;
    const int lm = lane & 15, quad = lane >> 4;

    ffrag acc[4][4];
    #pragma unroll
    for (int mi = 0; mi < 4; ++mi)
        #pragma unroll
        for (int ni = 0; ni < 4; ++ni)
            #pragma unroll
            for (int r = 0; r < 4; ++r) acc[mi][ni][r] = 0.f;

    const int srow = tid >> 1, shalf = tid & 1;
    const long aoff = (long)(bm + srow) * g.lda + shalf * 16;
    int brow = bn + srow; if (brow > g.N - 1) brow = g.N - 1;
    const long boff = (long)brow * g.ldb + shalf * 16;
    const int loff = srow * 40 + shalf * 16;

    uint4 va0, va1, vb0, vb1, wa0, wa1, wb0, wb1;
    va0 = *(const uint4*)(A + aoff);
    va1 = *(const uint4*)(A + aoff + 8);
    vb0 = *(const uint4*)(B + boff);
    vb1 = *(const uint4*)(B + boff + 8);
    if (three) {
        wa0 = *(const uint4*)(Alp + aoff);
        wa1 = *(const uint4*)(Alp + aoff + 8);
        wb0 = *(const uint4*)(Blp + boff);
        wb1 = *(const uint4*)(Blp + boff + 8);
    }

    for (int k0 = 0; k0 < g.K; k0 += 32) {
        __syncthreads();
        *(uint4*)(As + loff) = va0; *(uint4*)(As + loff + 8) = va1;
        *(uint4*)(Bs + loff) = vb0; *(uint4*)(Bs + loff + 8) = vb1;
        if (three) {
            *(uint4*)(Als + loff) = wa0; *(uint4*)(Als + loff + 8) = wa1;
            *(uint4*)(Bls + loff) = wb0; *(uint4*)(Bls + loff + 8) = wb1;
        }
        __syncthreads();
        if (k0 + 32 < g.K) {
            va0 = *(const uint4*)(A + aoff + k0 + 32);
            va1 = *(const uint4*)(A + aoff + k0 + 40);
            vb0 = *(const uint4*)(B + boff + k0 + 32);
            vb1 = *(const uint4*)(B + boff + k0 + 40);
            if (three) {
                wa0 = *(const uint4*)(Alp + aoff + k0 + 32);
                wa1 = *(const uint4*)(Alp + aoff + k0 + 40);
                wb0 = *(const uint4*)(Blp + boff + k0 + 32);
                wb1 = *(const uint4*)(Blp + boff + k0 + 40);
            }
        }
        if (three) {
            bfrag af[4], bf[4], al[4], bl[4];
            #pragma unroll
            for (int mi = 0; mi < 4; ++mi) {
                af[mi] = *(const bfrag*)(As  + (wm + mi * 16 + lm) * 40 + quad * 8);
                al[mi] = *(const bfrag*)(Als + (wm + mi * 16 + lm) * 40 + quad * 8);
            }
            #pragma unroll
            for (int ni = 0; ni < 4; ++ni) {
                bf[ni] = *(const bfrag*)(Bs  + (wn + ni * 16 + lm) * 40 + quad * 8);
                bl[ni] = *(const bfrag*)(Bls + (wn + ni * 16 + lm) * 40 + quad * 8);
            }
            #pragma unroll
            for (int mi = 0; mi < 4; ++mi)
                #pragma unroll
                for (int ni = 0; ni < 4; ++ni) {
                    acc[mi][ni] = __builtin_amdgcn_mfma_f32_16x16x32_bf16(af[mi], bf[ni], acc[mi][ni], 0, 0, 0);
                    acc[mi][ni] = __builtin_amdgcn_mfma_f32_16x16x32_bf16(af[mi], bl[ni], acc[mi][ni], 0, 0, 0);
                    acc[mi][ni] = __builtin_amdgcn_mfma_f32_16x16x32_bf16(al[mi], bf[ni], acc[mi][ni], 0, 0, 0);
                }
        } else {
            bfrag af[4], bf[4];
            #pragma unroll
            for (int mi = 0; mi < 4; ++mi)
                af[mi] = *(const bfrag*)(As + (wm + mi * 16 + lm) * 40 + quad * 8);
            #pragma unroll
            for (int ni = 0; ni < 4; ++ni)
                bf[ni] = *(const bfrag*)(Bs + (wn + ni * 16 + lm) * 40 + quad * 8);
            #pragma unroll
            for (int mi = 0; mi < 4; ++mi)
                #pragma unroll
                for (int ni = 0; ni < 4; ++ni)
                    acc[mi][ni] = __builtin_amdgcn_mfma_f32_16x16x32_bf16(af[mi], bf[ni], acc[mi][ni], 0, 0, 0);
        }
    }

    #pragma unroll
    for (int mi = 0; mi < 4; ++mi)
        #pragma unroll
        for (int ni = 0; ni < 4; ++ni) {
            int n = bn + wn + ni * 16 + lm;
            if (n < g.N) {
                int mb = bm + wm + mi * 16 + quad * 4;
                if (g.obf) {
                    unsigned short* C = (unsigned short*)g.C + (long)z * g.sC;
                    #pragma unroll
                    for (int r = 0; r < 4; ++r)
                        C[(long)(mb + r) * g.ldc + n] = f2bf(acc[mi][ni][r]);
                } else {
                    float* C = (float*)g.C + (long)z * g.sC;
                    #pragma unroll
                    for (int r = 0; r < 4; ++r)
                        C[(long)(mb + r) * g.ldc + n] = acc[mi][ni][r];
                }
            }
        }
}

// ---------------------------------------------------------------------------
// Merged transforms: blocks [0,4096) iq2, [4096,8192) ik2, [8192,9216) kv2.
// ---------------------------------------------------------------------------
__global__ __launch_bounds__(256) void mtrans_k(
    const float* __restrict__ iq, unsigned short* __restrict__ iqh, unsigned short* __restrict__ iql,
    const float* __restrict__ ik, unsigned short* __restrict__ ikh, unsigned short* __restrict__ ikl,
    const float* __restrict__ knw, const float* __restrict__ knb,
    const float* __restrict__ kva, unsigned short* __restrict__ kvb, const float* __restrict__ kvnw,
    const float* __restrict__ cosb, const float* __restrict__ sinb)
{
    __shared__ float red[256];
    __shared__ float rsh;
    const int b = blockIdx.x, tid = threadIdx.x;
    if (b < 8192) {
        const bool isq = b < 4096;
        int rb = isq ? b : b - 4096;
        int row = rb * 4 + (tid >> 6);
        int p = tid & 63;
        int t = row >> 4;
        const float* src = isq ? iq : ik;
        float a = src[(long)row * 128 + p];
        float bb = src[(long)row * 128 + 64 + p];
        if (!isq) {
            float ssum = a + bb;
            #pragma unroll
            for (int o = 1; o < 64; o <<= 1) ssum += __shfl_xor(ssum, o, 64);
            float m = ssum * (1.f / 128.f);
            float da = a - m, db = bb - m;
            float v = da * da + db * db;
            #pragma unroll
            for (int o = 1; o < 64; o <<= 1) v += __shfl_xor(v, o, 64);
            float r = rsqrtf(v * (1.f / 128.f) + 1e-5f);
            a = da * r * knw[p] + knb[p];
            bb = db * r * knw[64 + p] + knb[64 + p];
        }
        float c = cosb[t * 32 + (p & 31)], sn = sinb[t * 32 + (p & 31)];
        float asw = __shfl_xor(a, 32, 64);
        a = (p < 32) ? (a * c - asw * sn) : (asw * sn + a * c);
        #pragma unroll
        for (int h = 1; h < 64; h <<= 1) {
            float a2 = __shfl_xor(a, h, 64);
            float b2 = __shfl_xor(bb, h, 64);
            a = (p & h) ? (a2 - a) : (a + a2);
            bb = (p & h) ? (b2 - bb) : (bb + b2);
        }
        unsigned short* hi = isq ? iqh : ikh;
        unsigned short* lo = isq ? iql : ikl;
        unsigned short hb = f2bf(bb), ha = f2bf(a);
        hi[(long)row * 128 + p] = hb;
        hi[(long)row * 128 + 64 + p] = ha;
        lo[(long)row * 128 + p] = f2bf(bb - bf2f(hb));
        lo[(long)row * 128 + 64 + p] = f2bf(a - bf2f(ha));
    } else {
        int t = b - 8192;
        const float* a = kva + (long)t * CKV_;
        unsigned short* o = kvb + (long)t * CKV_;
        float v0 = a[tid], v1 = a[tid + 256];
        red[tid] = v0 * v0 + v1 * v1; __syncthreads();
        for (int off = 128; off; off >>= 1) { if (tid < off) red[tid] += red[tid + off]; __syncthreads(); }
        if (tid == 0) rsh = rsqrtf(red[0] / (float)KVLR_ + 1e-6f);
        __syncthreads();
        float rs = rsh;
        o[tid]       = f2bf(v0 * rs * kvnw[tid]);
        o[tid + 256] = f2bf(v1 * rs * kvnw[tid + 256]);
        if (tid < 32) {
            float x1 = a[512 + tid], x2 = a[544 + tid];
            float c = cosb[t * 32 + tid], sn = sinb[t * 32 + tid];
            o[512 + tid] = f2bf(x1 * c - x2 * sn);
            o[544 + tid] = f2bf(x1 * sn + x2 * c);
        }
    }
}

// ---------------------------------------------------------------------------
// Indexer score (MFMA bf16x3), BK=64, register-prefetch across (h,ks) steps.
// ---------------------------------------------------------------------------
__global__ __launch_bounds__(256) void score3_k(
    const unsigned short* __restrict__ iqh, const unsigned short* __restrict__ iql,
    const unsigned short* __restrict__ ikh, const unsigned short* __restrict__ ikl,
    const float* __restrict__ wtok, float* __restrict__ score)
{
    const int bt = blockIdx.y, bs = blockIdx.x;
    if (bs > bt) return;
    __shared__ unsigned short Ah[64 * 72], Al[64 * 72], Bh[64 * 72], Bl[64 * 72];
    __shared__ float wts[64][16];
    const int tid = threadIdx.x;
    const int wave = tid >> 6, lane = tid & 63;
    const int wm = (wave >> 1) * 32, wn = (wave & 1) * 32;
    const int lm = lane & 15, quad = lane >> 4;
    const int t0 = bt * 64, s0 = bs * 64;
    const int srow = tid >> 2, schunk = tid & 3;
    const int loff = srow * 72 + schunk * 8;

    for (int e = tid; e < 1024; e += 256)
        wts[e >> 4][e & 15] = wtok[(long)(t0 + (e >> 4)) * IH_ + (e & 15)];

    const long abase = (long)(t0 + srow) * 2048 + schunk * 8;
    const long bbase = (long)(s0 + srow) * 2048 + schunk * 8;

    uint4 pah0 = *(const uint4*)(iqh + abase);
    uint4 pah1 = *(const uint4*)(iqh + abase + 32);
    uint4 pal0 = *(const uint4*)(iql + abase);
    uint4 pal1 = *(const uint4*)(iql + abase + 32);
    uint4 pbh0 = *(const uint4*)(ikh + bbase);
    uint4 pbh1 = *(const uint4*)(ikh + bbase + 32);
    uint4 pbl0 = *(const uint4*)(ikl + bbase);
    uint4 pbl1 = *(const uint4*)(ikl + bbase + 32);

    float accf[2][2][4] = {};

    for (int h = 0; h < IH_; ++h) {
        ffrag acch[2][2];
        #pragma unroll
        for (int mi = 0; mi < 2; ++mi)
            #pragma unroll
            for (int ni = 0; ni < 2; ++ni)
                #pragma unroll
                for (int r = 0; r < 4; ++r) acch[mi][ni][r] = 0.f;

        #pragma unroll
        for (int k0 = 0; k0 < ID_; k0 += 64) {
            __syncthreads();
            *(uint4*)(Ah + loff) = pah0; *(uint4*)(Ah + loff + 32) = pah1;
            *(uint4*)(Al + loff) = pal0; *(uint4*)(Al + loff + 32) = pal1;
            *(uint4*)(Bh + loff) = pbh0; *(uint4*)(Bh + loff + 32) = pbh1;
            *(uint4*)(Bl + loff) = pbl0; *(uint4*)(Bl + loff + 32) = pbl1;
            __syncthreads();
            int step = h * 2 + (k0 >> 6) + 1;
            if (step < 32) {
                int off = (step >> 1) * 128 + (step & 1) * 64;
                pah0 = *(const uint4*)(iqh + abase + off);
                pah1 = *(const uint4*)(iqh + abase + off + 32);
                pal0 = *(const uint4*)(iql + abase + off);
                pal1 = *(const uint4*)(iql + abase + off + 32);
                pbh0 = *(const uint4*)(ikh + bbase + off);
                pbh1 = *(const uint4*)(ikh + bbase + off + 32);
                pbl0 = *(const uint4*)(ikl + bbase + off);
                pbl1 = *(const uint4*)(ikl + bbase + off + 32);
            }
            bfrag ahf[2][2], alf[2][2], bhf[2][2], blf[2][2];
            #pragma unroll
            for (int mi = 0; mi < 2; ++mi)
                #pragma unroll
                for (int ks = 0; ks < 2; ++ks) {
                    ahf[mi][ks] = *(const bfrag*)(Ah + (wm + mi * 16 + lm) * 72 + ks * 32 + quad * 8);
                    alf[mi][ks] = *(const bfrag*)(Al + (wm + mi * 16 + lm) * 72 + ks * 32 + quad * 8);
                }
            #pragma unroll
            for (int ni = 0; ni < 2; ++ni)
                #pragma unroll
                for (int ks = 0; ks < 2; ++ks) {
                    bhf[ni][ks] = *(const bfrag*)(Bh + (wn + ni * 16 + lm) * 72 + ks * 32 + quad * 8);
                    blf[ni][ks] = *(const bfrag*)(Bl + (wn + ni * 16 + lm) * 72 + ks * 32 + quad * 8);
                }
            #pragma unroll
            for (int mi = 0; mi < 2; ++mi)
                #pragma unroll
                for (int ni = 0; ni < 2; ++ni) {
                    acch[mi][ni] = __builtin_amdgcn_mfma_f32_16x16x32_bf16(ahf[mi][0], bhf[ni][0], acch[mi][ni], 0, 0, 0);
                    acch[mi][ni] = __builtin_amdgcn_mfma_f32_16x16x32_bf16(ahf[mi][0], blf[ni][0], acch[mi][ni], 0, 0, 0);
                    acch[mi][ni] = __builtin_amdgcn_mfma_f32_16x16x32_bf16(alf[mi][0], bhf[ni][0], acch[mi][ni], 0, 0, 0);
                    acch[mi][ni] = __builtin_amdgcn_mfma_f32_16x16x32_bf16(ahf[mi][1], bhf[ni][1], acch[mi][ni], 0, 0, 0);
                    acch[mi][ni] = __builtin_amdgcn_mfma_f32_16x16x32_bf16(ahf[mi][1], blf[ni][1], acch[mi][ni], 0, 0, 0);
                    acch[mi][ni] = __builtin_amdgcn_mfma_f32_16x16x32_bf16(alf[mi][1], bhf[ni][1], acch[mi][ni], 0, 0, 0);
                }
        }
        #pragma unroll
        for (int mi = 0; mi < 2; ++mi) {
            float wr[4];
            #pragma unroll
            for (int r = 0; r < 4; ++r) wr[r] = wts[wm + mi * 16 + quad * 4 + r][h];
            #pragma unroll
            for (int ni = 0; ni < 2; ++ni)
                #pragma unroll
                for (int r = 0; r < 4; ++r)
                    accf[mi][ni][r] += fmaxf(acch[mi][ni][r], 0.f) * wr[r];
        }
    }
    #pragma unroll
    for (int mi = 0; mi < 2; ++mi)
        #pragma unroll
        for (int ni = 0; ni < 2; ++ni) {
            int s = s0 + wn + ni * 16 + lm;
            int tb = t0 + wm + mi * 16 + quad * 4;
            #pragma unroll
            for (int r = 0; r < 4; ++r)
                score[(long)(tb + r) * T_ + s] = accf[mi][ni][r];
        }
}

// ---------------------------------------------------------------------------
// Top-256 per row via bitonic sort (ties -> lower index, matches jax top_k)
// ---------------------------------------------------------------------------
__global__ __launch_bounds__(512) void topk_k(const float* __restrict__ score, int* __restrict__ topk)
{
    int t = blockIdx.x, tid = threadIdx.x;
    __shared__ float v[1024];
    __shared__ int ix[1024];
    for (int i = tid; i < 1024; i += 512) {
        v[i] = (i <= t) ? score[(long)t * T_ + i] : -INFINITY;
        ix[i] = i;
    }
    __syncthreads();
    for (int k = 2; k <= 1024; k <<= 1) {
        for (int j = k >> 1; j > 0; j >>= 1) {
            for (int i = tid; i < 1024; i += 512) {
                int l = i ^ j;
                if (l > i) {
                    bool up = ((i & k) == 0);
                    float vi = v[i], vl = v[l];
                    int xi = ix[i], xl = ix[l];
                    bool iBetter = (vi > vl) || (vi == vl && xi < xl);
                    bool doSwap = up ? !iBetter : iBetter;
                    if (doSwap) { v[i] = vl; v[l] = vi; ix[i] = xl; ix[l] = xi; }
                }
            }
            __syncthreads();
        }
    }
    if (tid < 256) topk[(long)t * TOPK_ + tid] = ix[tid];
}

// ---------------------------------------------------------------------------
// Attention v7b (MFMA bf16): bf16 Q input; phase A depth-3 reg ring,
// phase B dbuf VT + raw barriers. Unchanged (parked at ~75 us).
// ---------------------------------------------------------------------------
__global__ __launch_bounds__(256, 4) void attn3_k(
    const unsigned short* __restrict__ qkeyb, const unsigned short* __restrict__ kvb,
    const int* __restrict__ topkp, unsigned short* __restrict__ olat)
{
    __shared__ __align__(16) unsigned short U[13568];
    __shared__ float red[16 * 17];
    __shared__ int kidx[256];
    unsigned short* Qbf = U;                    // [16][584] (phase A)
    float*          Lg  = (float*)U;            // [16][260] (after phase A)
    unsigned short* VT0 = U;                    // [128][36] (phase B buf 0)
    unsigned short* VT1 = U + 4608;             // [128][36] (phase B buf 1)
    unsigned short* Pbf = U + 9344;             // [16][264]

    const int t = blockIdx.x, tid = threadIdx.x;
    const int wave = tid >> 6, lane = tid & 63;
    const int lm = lane & 15, quad = lane >> 4;

    kidx[tid] = topkp[(long)t * TOPK_ + tid];
    const uint2* q2 = (const uint2*)(qkeyb + (long)t * (H_ * CKV_));
    #pragma unroll
    for (int rep = 0; rep < 9; ++rep) {
        int e = rep * 256 + tid;
        uint2 v = q2[e];
        int f = e * 4, h = f / CKV_, c = f - h * CKV_;
        *(uint2*)(Qbf + h * 584 + c) = v;
    }
    int myk0 = topkp[(long)t * TOPK_ + wave * 64 + 0 * 16 + lm];
    int myk1 = topkp[(long)t * TOPK_ + wave * 64 + 1 * 16 + lm];
    int myk2 = topkp[(long)t * TOPK_ + wave * 64 + 2 * 16 + lm];
    int myk3 = topkp[(long)t * TOPK_ + wave * 64 + 3 * 16 + lm];
    __syncthreads();

    ffrag acc[4];
    #pragma unroll
    for (int ni = 0; ni < 4; ++ni)
        #pragma unroll
        for (int r = 0; r < 4; ++r) acc[ni][r] = 0.f;

    const unsigned short* kb0 = kvb + (long)myk0 * CKV_ + quad * 8;
    const unsigned short* kb1 = kvb + (long)myk1 * CKV_ + quad * 8;
    const unsigned short* kb2 = kvb + (long)myk2 * CKV_ + quad * 8;
    const unsigned short* kb3 = kvb + (long)myk3 * CKV_ + quad * 8;

    bfrag ba[4], bb[4], bc[4];
    #define LDT(DST, C) { \
        DST[0] = *(const bfrag*)(kb0 + (C)); \
        DST[1] = *(const bfrag*)(kb1 + (C)); \
        DST[2] = *(const bfrag*)(kb2 + (C)); \
        DST[3] = *(const bfrag*)(kb3 + (C)); }
    #define PHA_STEP(I, BUF) { \
        bfrag af = *(const bfrag*)(Qbf + lm * 584 + (I) * 32 + quad * 8); \
        _Pragma("unroll") \
        for (int ni = 0; ni < 4; ++ni) \
            acc[ni] = __builtin_amdgcn_mfma_f32_16x16x32_bf16(af, BUF[ni], acc[ni], 0, 0, 0); \
        if ((I) < 15) LDT(BUF, (I) * 32 + 96) }

    LDT(ba, 0) LDT(bb, 32) LDT(bc, 64)
    PHA_STEP(0, ba)  PHA_STEP(1, bb)  PHA_STEP(2, bc)
    PHA_STEP(3, ba)  PHA_STEP(4, bb)  PHA_STEP(5, bc)
    PHA_STEP(6, ba)  PHA_STEP(7, bb)  PHA_STEP(8, bc)
    PHA_STEP(9, ba)  PHA_STEP(10, bb) PHA_STEP(11, bc)
    PHA_STEP(12, ba) PHA_STEP(13, bb) PHA_STEP(14, bc)
    PHA_STEP(15, ba) PHA_STEP(16, bb) PHA_STEP(17, bc)
    #undef PHA_STEP
    #undef LDT

    __syncthreads();
    #pragma unroll
    for (int ni = 0; ni < 4; ++ni)
        #pragma unroll
        for (int r = 0; r < 4; ++r)
            Lg[(quad * 4 + r) * 260 + wave * 64 + ni * 16 + lm] = acc[ni][r];
    __syncthreads();

    {
        int h = tid >> 4, j = tid & 15;
        float m = -INFINITY;
        #pragma unroll
        for (int kk = 0; kk < 16; ++kk) {
            int key = j * 16 + kk;
            if (kidx[key] <= t) m = fmaxf(m, Lg[h * 260 + key]);
        }
        red[h * 17 + j] = m;
        __syncthreads();
        float mh = -INFINITY;
        #pragma unroll
        for (int jj = 0; jj < 16; ++jj) mh = fmaxf(mh, red[h * 17 + jj]);
        __syncthreads();
        float s = 0.f;
        float pv[16];
        #pragma unroll
        for (int kk = 0; kk < 16; ++kk) {
            int key = j * 16 + kk;
            float e = (kidx[key] <= t) ? expf(Lg[h * 260 + key] * SCALE_LOG - mh * SCALE_LOG) : 0.f;
            pv[kk] = e; s += e;
        }
        red[h * 17 + j] = s;
        __syncthreads();
        float sh = 0.f;
        #pragma unroll
        for (int jj = 0; jj < 16; ++jj) sh += red[h * 17 + jj];
        float inv = 1.f / sh;
        #pragma unroll
        for (int kk = 0; kk < 16; ++kk)
            Pbf[h * 264 + j * 16 + kk] = f2bf(pv[kk] * inv);
    }

    const int kpair = tid & 15, cgrp = tid >> 4;
    ffrag acc2[2];
    #pragma unroll
    for (int ci = 0; ci < 2; ++ci)
        #pragma unroll
        for (int r = 0; r < 4; ++r) acc2[ci][r] = 0.f;

    uint4 ga0, gb0, ga1, gb1;
    #define PREFB(GA, GB, IT) { \
        int ka_ = kidx[((IT) & 7) * 32 + 2 * kpair]; \
        int kb_ = kidx[((IT) & 7) * 32 + 2 * kpair + 1]; \
        long co_ = (long)(((IT) >> 3) * 128 + cgrp * 8); \
        GA = *(const uint4*)(kvb + (long)ka_ * CKV_ + co_); \
        GB = *(const uint4*)(kvb + (long)kb_ * CKV_ + co_); }
    #define STOREB(GA, GB, BUF) { \
        const unsigned short* pa_ = (const unsigned short*)&GA; \
        const unsigned short* pb_ = (const unsigned short*)&GB; \
        _Pragma("unroll") \
        for (int i_ = 0; i_ < 8; ++i_) \
            *(unsigned int*)((BUF) + (cgrp * 8 + i_) * 36 + 2 * kpair) = \
                (unsigned int)pa_[i_] | ((unsigned int)pb_[i_] << 16); }
    #define MFMAB(BUF, IT) { \
        bfrag pa = *(const bfrag*)(Pbf + lm * 264 + ((IT) & 7) * 32 + quad * 8); \
        _Pragma("unroll") \
        for (int ci = 0; ci < 2; ++ci) { \
            int c = wave * 32 + ci * 16 + lm; \
            bfrag bv; \
            ((uint2*)&bv)[0] = *(const uint2*)((BUF) + c * 36 + quad * 8); \
            ((uint2*)&bv)[1] = *(const uint2*)((BUF) + c * 36 + quad * 8 + 4); \
            acc2[ci] = __builtin_amdgcn_mfma_f32_16x16x32_bf16(pa, bv, acc2[ci], 0, 0, 0); } }
    #define OLATST(IT) { \
        int p_ = (IT) >> 3; \
        _Pragma("unroll") \
        for (int ci = 0; ci < 2; ++ci) \
            _Pragma("unroll") \
            for (int r = 0; r < 4; ++r) \
                olat[((long)t * H_ + quad * 4 + r) * 512 + p_ * 128 + wave * 32 + ci * 16 + lm] \
                    = f2bf(acc2[ci][r]); \
        _Pragma("unroll") \
        for (int ci = 0; ci < 2; ++ci) \
            _Pragma("unroll") \
            for (int r = 0; r < 4; ++r) acc2[ci][r] = 0.f; }
    #define LGKBAR() { asm volatile("s_waitcnt lgkmcnt(0)" ::: "memory"); \
                       __builtin_amdgcn_s_barrier(); }

    PREFB(ga0, gb0, 0);
    PREFB(ga1, gb1, 1);
    LGKBAR();
    STOREB(ga0, gb0, VT0);
    LGKBAR();
    for (int it = 0; it < 32; it += 2) {
        STOREB(ga1, gb1, VT1);
        MFMAB(VT0, it);
        if (it + 2 < 32) PREFB(ga0, gb0, it + 2);
        LGKBAR();
        if (it + 2 < 32) STOREB(ga0, gb0, VT0);
        MFMAB(VT1, it + 1);
        if (it + 3 < 32) PREFB(ga1, gb1, it + 3);
        if (((it + 1) & 7) == 7) OLATST(it + 1);
        LGKBAR();
    }
    #undef PREFB
    #undef STOREB
    #undef MFMAB
    #undef OLATST
    #undef LGKBAR
}

// ---------------------------------------------------------------------------
extern "C" void kernel_launch(void* const* d_in, const int* in_sizes, int n_in,
                              void* d_out, int out_size, void* d_ws, size_t ws_size,
                              hipStream_t stream)
{
    const float* x          = (const float*)d_in[0];
    const float* cosb       = (const float*)d_in[1];
    const float* sinb       = (const float*)d_in[2];
    const float* wq_a       = (const float*)d_in[3];
    const float* q_norm_w   = (const float*)d_in[4];
    const float* wq_b       = (const float*)d_in[5];
    const float* wkv_a      = (const float*)d_in[6];
    const float* kv_norm_w  = (const float*)d_in[7];
    const float* wkv_b      = (const float*)d_in[8];
    const float* wo         = (const float*)d_in[9];
    const float* iq_norm_w  = (const float*)d_in[10];
    const float* iwq_b      = (const float*)d_in[11];
    const float* iwk        = (const float*)d_in[12];
    const float* k_norm_w   = (const float*)d_in[13];
    const float* k_norm_b   = (const float*)d_in[14];
    const float* wproj      = (const float*)d_in[15];
    float* out = (float*)d_out;

    // fp32 workspace (float offsets)
    float* ws    = (float*)d_ws;
    float* qr    = ws;                      // 1,048,576 (dead after qrnorm -> kvb slot)
    float* wtok  = ws + 1049600;
    int*   topk  = (int*)(ws + 1655808);    // 262,144 ints
    float* qkey  = ws + 1917952;            // 9,437,184 floats (bf16 sublayout region)
    float* outv  = ws + 11355136;           // 2,097,152 (slot)
    float* U0    = ws + 13452288;           // union region
    float* iq    = U0;                      // 2,097,152
    float* ik    = U0 + 2097152;            // 2,097,152
    float* kva   = U0 + 4194304;            // 589,824
    float* qbuf  = U0 + 4784128;            // 3,145,728
    float* score = U0 + 7929856;            // 1,048,576

    // bf16 sublayouts (ushort units) in the qkey region
    unsigned short* qkey_u = (unsigned short*)qkey;
    unsigned short* wqa_hi  = qkey_u;
    unsigned short* wqa_lo  = qkey_u + 2097152;
    unsigned short* iwk_hi  = qkey_u + 4194304;
    unsigned short* iwk_lo  = qkey_u + 8388608;
    unsigned short* iwqb_hi = qkey_u + 12582912;
    unsigned short* iwqb_lo = qkey_u + 14680064;
    unsigned short* qriq_hi = qkey_u + 16777216;
    unsigned short* qriq_lo = qkey_u + 17825792;
    unsigned short* iqbf_hi = qkey_u;
    unsigned short* iqbf_lo = qkey_u + 2097152;
    unsigned short* ikbf_hi = qkey_u + 4194304;
    unsigned short* ikbf_lo = qkey_u + 6291456;
    unsigned short* qkey_bf = qkey_u;                    // 9,437,184 ushorts
    unsigned short* wkvb_bf = qkey_u + 9437184;          // 2,097,152 (over dead iwk_lo)
    unsigned short* wo_bf   = qkey_u;                    // qkey region dead after attn3
    unsigned short* q_u     = (unsigned short*)qbuf;
    unsigned short* x_hi    = q_u;
    unsigned short* x_lo    = q_u + 2097152;
    unsigned short* wkva_hi = q_u + 4194304;
    unsigned short* outv_u  = (unsigned short*)outv;
    unsigned short* wqb_hi  = outv_u;
    unsigned short* qrq_hi  = outv_u + 3145728;
    unsigned short* outv_bf = outv_u;
    unsigned short* qbf     = (unsigned short*)iq;
    unsigned short* wkT     = (unsigned short*)ik;
    unsigned short* kvb     = (unsigned short*)qr;
    unsigned short* olat_bf = (unsigned short*)U0;

    // ---- 1. mega-cast 1 ----
    {
        CastDesc d;
        d.seg[0] = { x,      x_hi,    x_lo    };
        d.seg[1] = { wq_a,   wqa_hi,  wqa_lo  };
        d.seg[2] = { iwk,    iwk_hi,  iwk_lo  };
        d.seg[3] = { iwq_b,  iwqb_hi, iwqb_lo };
        d.seg[4] = { wkv_a,  wkva_hi, nullptr };
        d.seg[5] = { wq_b,   wqb_hi,  nullptr };
        d.bstart[0] = 0;     d.bstart[1] = 2048;  d.bstart[2] = 4096;
        d.bstart[3] = 8192;  d.bstart[4] = 10240; d.bstart[5] = 11392;
        d.bstart[6] = 14464; d.nseg = 6;
        castm_k<<<14464, 256, 0, stream>>>(d);
    }

    // ---- 2. Launch A: qr(128^2 bf16x3) + ik(128^2 bf16x3) + wtok ----
    {
        GDesc d{};
        d.nseg = 3;
        d.bstart[0] = 0; d.bstart[1] = 64; d.bstart[2] = 192; d.bstart[3] = 1216;
        GSeg& s0 = d.seg[0];
        s0.A = x_hi; s0.Al = x_lo; s0.B = wqa_hi; s0.Bl = wqa_lo; s0.C = qr;
        s0.lda = DIM_; s0.ldb = DIM_; s0.ldc = QLR_; s0.N = QLR_; s0.K = DIM_;
        s0.bnx = 8; s0.bmx = 8; s0.mode = 1; s0.obf = 0;          // 64 blocks
        GSeg& s1 = d.seg[1];
        s1.A = x_hi; s1.Al = x_lo; s1.B = iwk_hi; s1.Bl = iwk_lo; s1.C = ik;
        s1.lda = DIM_; s1.ldb = DIM_; s1.ldc = IH_ * ID_; s1.N = IH_ * ID_; s1.K = DIM_;
        s1.bnx = 16; s1.bmx = 8; s1.mode = 1; s1.obf = 0;         // 128 blocks
        GSeg& s2 = d.seg[2];
        s2.A = x; s2.B = wproj; s2.C = wtok; s2.mode = 3;         // 1024 blocks
        mgemm_k<<<1216, 256, 0, stream>>>(d);
    }

    // ---- 3. fused rstd + qriq(hi/lo) + qrq(hi) ----
    qrnorm_k<<<T_, 256, 0, stream>>>(qr, iq_norm_w, q_norm_w, qriq_hi, qriq_lo, qrq_hi);

    // ---- 4. Launch B1: iq(128^2 bf16x3) + kva(128^2 bf16, N guard) + wkv_b cast ----
    {
        GDesc d{};
        d.nseg = 3;
        d.bstart[0] = 0; d.bstart[1] = 128; d.bstart[2] = 168; d.bstart[3] = 2216;
        GSeg& s0 = d.seg[0];
        s0.A = qriq_hi; s0.Al = qriq_lo; s0.B = iwqb_hi; s0.Bl = iwqb_lo; s0.C = iq;
        s0.lda = QLR_; s0.ldb = QLR_; s0.ldc = IH_ * ID_; s0.N = IH_ * ID_; s0.K = QLR_;
        s0.bnx = 16; s0.bmx = 8; s0.mode = 1; s0.obf = 0;         // 128 blocks
        GSeg& s1 = d.seg[1];
        s1.A = x_hi; s1.B = wkva_hi; s1.C = kva;
        s1.lda = DIM_; s1.ldb = DIM_; s1.ldc = CKV_; s1.N = CKV_; s1.K = DIM_;
        s1.bnx = 5; s1.bmx = 8; s1.mode = 0; s1.obf = 0;          // 40 blocks (N=576 guard)
        GSeg& s2 = d.seg[2];
        s2.A = wkv_b; s2.C = wkvb_bf; s2.C2 = nullptr; s2.mode = 2;   // 2048 blocks
        mgemm_k<<<2216, 256, 0, stream>>>(d);
    }

    // ---- 5. Launch B2: q = rmsnorm(qr,q_norm) @ wq_b.T (128^2 bf16) ----
    {
        GDesc d{};
        d.nseg = 1;
        d.bstart[0] = 0; d.bstart[1] = 192;
        GSeg& s0 = d.seg[0];
        s0.A = qrq_hi; s0.B = wqb_hi; s0.C = qbuf;
        s0.lda = QLR_; s0.ldb = QLR_; s0.ldc = H_ * QKD_; s0.N = H_ * QKD_; s0.K = QLR_;
        s0.bnx = 24; s0.bmx = 8; s0.mode = 0; s0.obf = 0;         // 192 blocks
        mgemm_k<<<192, 256, 0, stream>>>(d);
    }

    // ---- 6. merged transforms ----
    mtrans_k<<<9216, 256, 0, stream>>>(iq, iqbf_hi, iqbf_lo, ik, ikbf_hi, ikbf_lo,
                                       k_norm_w, k_norm_b, kva, kvb, kv_norm_w, cosb, sinb);

    // ---- 7/8. score + topk ----
    score3_k<<<dim3(T_/64, T_/64), 256, 0, stream>>>(iqbf_hi, iqbf_lo, ikbf_hi, ikbf_lo, wtok, score);
    topk_k<<<T_, 512, 0, stream>>>(score, topk);

    // ---- 9. qbuf cast + tcast + qpe (one launch) ----
    {
        GDesc d{};
        d.nseg = 3;
        d.bstart[0] = 0; d.bstart[1] = 3072; d.bstart[2] = 4096; d.bstart[3] = 6144;
        GSeg& s0 = d.seg[0];
        s0.A = qbuf; s0.C = qbf; s0.C2 = nullptr; s0.mode = 2;      // 3072 blocks
        GSeg& s1 = d.seg[1];
        s1.A = wkv_b; s1.C = wkT; s1.mode = 4;                      // 1024 blocks
        GSeg& s2 = d.seg[2];
        s2.A = qbuf; s2.B = cosb; s2.Bl = sinb; s2.C = qkey_bf; s2.mode = 5;  // 2048 blocks
        mgemm_k<<<6144, 256, 0, stream>>>(d);
    }

    // ---- 10. q_nope_proj (128^2 batched) ----
    gemm_bt_mfma_k<<<dim3(KVLR_/128, T_/128, H_), 256, 0, stream>>>(
        qbf, wkT, qkey_bf, 192L, 65536L, 576L, H_*QKD_, ID_, H_*CKV_, KVLR_, ID_, 1);

    // ---- 11. attention -> olat bf16 @ U0 ----
    attn3_k<<<T_, 256, 0, stream>>>(qkey_bf, kvb, topk, olat_bf);

    // ---- 12. Launch D: outv GEMM (128^2 batched, bf16 out) + wo cast ----
    {
        GDesc d{};
        d.nseg = 2;
        d.bstart[0] = 0; d.bstart[1] = 128; d.bstart[2] = 4224;
        GSeg& s0 = d.seg[0];
        s0.A = olat_bf; s0.B = wkvb_bf + (long)NOPE_ * KVLR_; s0.C = outv_bf;
        s0.sA = 512; s0.sB = (long)(NOPE_ + VD_) * KVLR_; s0.sC = VD_;
        s0.lda = H_ * KVLR_; s0.ldb = KVLR_; s0.ldc = H_ * VD_; s0.N = VD_; s0.K = KVLR_;
        s0.bnx = 1; s0.bmx = 8; s0.mode = 0; s0.obf = 1;          // 8x16z = 128 blocks
        GSeg& s1 = d.seg[1];
        s1.A = wo; s1.C = wo_bf; s1.C2 = nullptr; s1.mode = 2;      // 4096 blocks
        mgemm_k<<<4224, 256, 0, stream>>>(d);
    }

    // ---- 13. out = outv @ wo.T (128^2 bf16) ----
    {
        GDesc d{};
        d.nseg = 1;
        d.bstart[0] = 0; d.bstart[1] = 128;
        GSeg& s0 = d.seg[0];
        s0.A = outv_bf; s0.B = wo_bf; s0.C = out;
        s0.lda = H_ * VD_; s0.ldb = H_ * VD_; s0.ldc = DIM_; s0.N = DIM_; s0.K = H_ * VD_;
        s0.bnx = 16; s0.bmx = 8; s0.mode = 0; s0.obf = 0;         // 128 blocks
        mgemm_k<<<128, 256, 0, stream>>>(d);
    }

    (void)in_sizes; (void)n_in; (void)out_size; (void)ws_size;
}

// Round 11
// 489.123 us; speedup vs baseline: 1.1736x; 1.1736x over previous
//
#include <hip/hip_runtime.h>
#include <hip/hip_bf16.h>
#include <math.h>

// Problem constants
#define T_     1024
#define DIM_   2048
#define H_     16
#define QLR_   1024
#define KVLR_  512
#define NOPE_  128
#define ROPE_  64
#define VD_    128
#define QKD_   192   // NOPE+ROPE
#define IH_    16
#define ID_    128
#define TOPK_  256
#define CKV_   576   // KVLR + ROPE

#define SCALE_W    0.022097086912079608f   // IH^-0.5 * ID^-0.5
#define SCALE_LOG  0.07216878364870323f    // QKD^-0.5

typedef short bfrag __attribute__((ext_vector_type(8)));   // 8 bf16 = 4 VGPRs
typedef float ffrag __attribute__((ext_vector_type(4)));   // 4 fp32 acc

__device__ __forceinline__ unsigned short f2bf(float f) {
    union { __hip_bfloat16 h; unsigned short u; } c; c.h = __float2bfloat16(f); return c.u;
}
__device__ __forceinline__ float bf2f(unsigned short u) {
    union { unsigned short u; __hip_bfloat16 h; } c; c.u = u; return __bfloat162float(c.h);
}

// ---------------------------------------------------------------------------
// Multi-segment cast: N independent fp32->bf16 (hi or hi+lo) casts, 1 launch.
// ---------------------------------------------------------------------------
struct CastSeg { const float* src; unsigned short* hi; unsigned short* lo; };
struct CastDesc { CastSeg seg[6]; int bstart[7]; int nseg; };

__global__ __launch_bounds__(256) void castm_k(CastDesc d)
{
    int b = blockIdx.x, s = 0;
    #pragma unroll
    for (int i = 1; i < 6; ++i) if (i < d.nseg && b >= d.bstart[i]) s = i;
    long base = ((long)(b - d.bstart[s]) * 256 + threadIdx.x) * 4;
    float4 v = *(const float4*)(d.seg[s].src + base);
    ushort4 h4;
    h4.x = f2bf(v.x); h4.y = f2bf(v.y); h4.z = f2bf(v.z); h4.w = f2bf(v.w);
    *(ushort4*)(d.seg[s].hi + base) = h4;
    if (d.seg[s].lo) {
        ushort4 l4;
        l4.x = f2bf(v.x - bf2f(h4.x));
        l4.y = f2bf(v.y - bf2f(h4.y));
        l4.z = f2bf(v.z - bf2f(h4.z));
        l4.w = f2bf(v.w - bf2f(h4.w));
        *(ushort4*)(d.seg[s].lo + base) = l4;
    }
}

// ---------------------------------------------------------------------------
// Fused rstd + both qr casts: one block per token row (1024 cols).
// ---------------------------------------------------------------------------
__global__ __launch_bounds__(256) void qrnorm_k(const float* __restrict__ qr,
    const float* __restrict__ iqw, const float* __restrict__ qw,
    unsigned short* __restrict__ qriq_hi, unsigned short* __restrict__ qriq_lo,
    unsigned short* __restrict__ qrq_hi)
{
    int t = blockIdx.x, tid = threadIdx.x;
    long base = (long)t * QLR_ + tid * 4;
    float4 v = *(const float4*)(qr + base);
    __shared__ float red[256];
    red[tid] = v.x * v.x + v.y * v.y + v.z * v.z + v.w * v.w;
    __syncthreads();
    for (int off = 128; off; off >>= 1) { if (tid < off) red[tid] += red[tid + off]; __syncthreads(); }
    float r = rsqrtf(red[0] / (float)QLR_ + 1e-6f);
    int col = tid * 4;
    float4 wi = *(const float4*)(iqw + col);
    float4 wq = *(const float4*)(qw + col);
    float s[4] = {v.x, v.y, v.z, v.w};
    float wiv[4] = {wi.x, wi.y, wi.z, wi.w};
    float wqv[4] = {wq.x, wq.y, wq.z, wq.w};
    ushort4 h4, l4, g4;
    unsigned short* hp = (unsigned short*)&h4;
    unsigned short* lp = (unsigned short*)&l4;
    unsigned short* gp = (unsigned short*)&g4;
    #pragma unroll
    for (int i = 0; i < 4; ++i) {
        float ai = s[i] * wiv[i] * r;
        float aq = s[i] * wqv[i] * r;
        hp[i] = f2bf(ai);
        lp[i] = f2bf(ai - bf2f(hp[i]));
        gp[i] = f2bf(aq);
    }
    *(ushort4*)(qriq_hi + base) = h4;
    *(ushort4*)(qriq_lo + base) = l4;
    *(ushort4*)(qrq_hi + base) = g4;
}

// ---------------------------------------------------------------------------
// MFMA bf16 NT GEMM, 128x128 tile (batched q_nope_proj, K=128). BK=32.
// ---------------------------------------------------------------------------
__global__ __launch_bounds__(256) void gemm_bt_mfma_k(
    const unsigned short* __restrict__ A, const unsigned short* __restrict__ B,
    void* __restrict__ Cv, long sA, long sB, long sC,
    int lda, int ldb, int ldc, int N, int K, int obf)
{
    A += (long)blockIdx.z * sA;
    B += (long)blockIdx.z * sB;
    __shared__ unsigned short As[128 * 40];
    __shared__ unsigned short Bs[128 * 40];
    const int tid = threadIdx.x;
    const int bm = blockIdx.y * 128, bn = blockIdx.x * 128;
    const int wave = tid >> 6, lane = tid & 63;
    const int wm = (wave >> 1) * 64, wn = (wave & 1) * 64;
    const int lm = lane & 15, quad = lane >> 4;

    ffrag acc[4][4];
    #pragma unroll
    for (int mi = 0; mi < 4; ++mi)
        #pragma unroll
        for (int ni = 0; ni < 4; ++ni)
            #pragma unroll
            for (int r = 0; r < 4; ++r) acc[mi][ni][r] = 0.f;

    const int srow = tid >> 1, shalf = tid & 1;
    const long aoff = (long)(bm + srow) * lda + shalf * 16;
    int brow = bn + srow; if (brow > N - 1) brow = N - 1;
    const long boff = (long)brow * ldb + shalf * 16;
    unsigned short* la = As + srow * 40 + shalf * 16;
    unsigned short* lb = Bs + srow * 40 + shalf * 16;

    uint4 va0 = *(const uint4*)(A + aoff);
    uint4 va1 = *(const uint4*)(A + aoff + 8);
    uint4 vb0 = *(const uint4*)(B + boff);
    uint4 vb1 = *(const uint4*)(B + boff + 8);

    for (int k0 = 0; k0 < K; k0 += 32) {
        __syncthreads();
        *(uint4*)la = va0; *(uint4*)(la + 8) = va1;
        *(uint4*)lb = vb0; *(uint4*)(lb + 8) = vb1;
        __syncthreads();
        if (k0 + 32 < K) {
            va0 = *(const uint4*)(A + aoff + k0 + 32);
            va1 = *(const uint4*)(A + aoff + k0 + 40);
            vb0 = *(const uint4*)(B + boff + k0 + 32);
            vb1 = *(const uint4*)(B + boff + k0 + 40);
        }
        bfrag af[4], bf[4];
        #pragma unroll
        for (int mi = 0; mi < 4; ++mi)
            af[mi] = *(const bfrag*)(As + (wm + mi * 16 + lm) * 40 + quad * 8);
        #pragma unroll
        for (int ni = 0; ni < 4; ++ni)
            bf[ni] = *(const bfrag*)(Bs + (wn + ni * 16 + lm) * 40 + quad * 8);
        #pragma unroll
        for (int mi = 0; mi < 4; ++mi)
            #pragma unroll
            for (int ni = 0; ni < 4; ++ni)
                acc[mi][ni] = __builtin_amdgcn_mfma_f32_16x16x32_bf16(
                    af[mi], bf[ni], acc[mi][ni], 0, 0, 0);
    }

    #pragma unroll
    for (int mi = 0; mi < 4; ++mi)
        #pragma unroll
        for (int ni = 0; ni < 4; ++ni) {
            int n = bn + wn + ni * 16 + lm;
            if (n < N) {
                int mb = bm + wm + mi * 16 + quad * 4;
                if (obf) {
                    unsigned short* C = (unsigned short*)Cv + (long)blockIdx.z * sC;
                    #pragma unroll
                    for (int r = 0; r < 4; ++r)
                        C[(long)(mb + r) * ldc + n] = f2bf(acc[mi][ni][r]);
                } else {
                    float* C = (float*)Cv + (long)blockIdx.z * sC;
                    #pragma unroll
                    for (int r = 0; r < 4; ++r)
                        C[(long)(mb + r) * ldc + n] = acc[mi][ni][r];
                }
            }
        }
}

// ---------------------------------------------------------------------------
// Multi-segment fused kernel (round-8 body: GEMM 64x64 BK=64 depth-1,
// 72-ushort LDS stride -- the measured-best config for these M=1024 shapes).
// modes: 0=gemm bf16, 1=gemm bf16x3, 2=cast f32->bf16(hi[,lo]),
//        3=wtok, 4=tcast(wkv_b->wkT), 5=qpe
// ---------------------------------------------------------------------------
struct GSeg {
    const void* A; const void* Al; const void* B; const void* Bl;
    void* C; void* C2;
    long sA, sB, sC;
    int lda, ldb, ldc, N, K, bnx, bmx, mode, obf;
};
struct GDesc { GSeg seg[4]; int bstart[5]; int nseg; };

__global__ __launch_bounds__(256) void mgemm_k(GDesc d)
{
    __shared__ unsigned short Ahs[64 * 72], Als[64 * 72], Bhs[64 * 72], Bls[64 * 72];
    const int tid = threadIdx.x;
    const int b = blockIdx.x;
    int s = 0;
    #pragma unroll
    for (int i = 1; i < 4; ++i) if (i < d.nseg && b >= d.bstart[i]) s = i;
    const int rel = b - d.bstart[s];
    const int mode = d.seg[s].mode;

    if (mode == 2) {   // fp32 -> bf16 cast (hi [, lo])
        const float* src = (const float*)d.seg[s].A;
        unsigned short* hi = (unsigned short*)d.seg[s].C;
        unsigned short* lo = (unsigned short*)d.seg[s].C2;
        long base = ((long)rel * 256 + tid) * 4;
        float4 v = *(const float4*)(src + base);
        ushort4 h4;
        h4.x = f2bf(v.x); h4.y = f2bf(v.y); h4.z = f2bf(v.z); h4.w = f2bf(v.w);
        *(ushort4*)(hi + base) = h4;
        if (lo) {
            ushort4 l4;
            l4.x = f2bf(v.x - bf2f(h4.x));
            l4.y = f2bf(v.y - bf2f(h4.y));
            l4.z = f2bf(v.z - bf2f(h4.z));
            l4.w = f2bf(v.w - bf2f(h4.w));
            *(ushort4*)(lo + base) = l4;
        }
        return;
    }
    if (mode == 3) {   // wtok
        const float* x = (const float*)d.seg[s].A;
        const float* wproj = (const float*)d.seg[s].B;
        float* wt = (float*)d.seg[s].C;
        float* xs = (float*)Ahs;           // 2048 floats = 8KB <= 9216B
        int t = rel;
        for (int c = tid; c < DIM_; c += 256) xs[c] = x[(long)t * DIM_ + c];
        __syncthreads();
        int wave = tid >> 6, lane = tid & 63;
        #pragma unroll
        for (int i = 0; i < 4; ++i) {
            int h = wave * 4 + i;
            float sum = 0.f;
            for (int c = lane; c < DIM_; c += 64) sum += xs[c] * wproj[(long)h * DIM_ + c];
            for (int off = 32; off; off >>= 1) sum += __shfl_xor(sum, off, 64);
            if (lane == 0) wt[(long)t * IH_ + h] = sum * SCALE_W;
        }
        return;
    }
    if (mode == 4) {   // tcast: wkT[h][c][d] = bf16(wkv_b[(h*256+d)*512+c])
        const float* in = (const float*)d.seg[s].A;
        unsigned short* out = (unsigned short*)d.seg[s].C;
        int h = rel >> 6, c0 = (rel & 15) * 32, d0 = ((rel >> 4) & 3) * 32;
        float (*tt)[33] = (float(*)[33])(void*)Ahs;   // 4224B <= 9216B
        int tx = tid & 31, ty = tid >> 5;
        #pragma unroll
        for (int i = 0; i < 4; ++i)
            tt[ty + i * 8][tx] = in[(long)(h * 256 + d0 + ty + i * 8) * 512 + c0 + tx];
        __syncthreads();
        #pragma unroll
        for (int i = 0; i < 4; ++i)
            out[((long)h * 512 + c0 + ty + i * 8) * 128 + d0 + tx] = f2bf(tt[tx][ty + i * 8]);
        return;
    }
    if (mode == 5) {   // qpe: 8 rows per block, 32 lanes per row
        const float* q = (const float*)d.seg[s].A;
        const float* cosb = (const float*)d.seg[s].B;
        const float* sinb = (const float*)d.seg[s].Bl;
        unsigned short* qk = (unsigned short*)d.seg[s].C;
        int row = rel * 8 + (tid >> 5);
        int i = tid & 31;
        int t = row / H_;
        const float* qp = q + (long)row * QKD_ + NOPE_;
        float x1 = qp[i], x2 = qp[i + 32];
        float c = cosb[t * 32 + i], sn = sinb[t * 32 + i];
        unsigned short* o = qk + (long)row * CKV_ + 512;
        o[i]      = f2bf(x1 * c - x2 * sn);
        o[i + 32] = f2bf(x1 * sn + x2 * c);
        return;
    }

    // ---- GEMM modes 0 / 1 (64x64 tile, BK=64, 72-ushort LDS stride) ----
    const GSeg g = d.seg[s];
    const bool three = (mode == 1);
    const int per = g.bnx * g.bmx;
    const int z = rel / per;
    const int r2 = rel - z * per;
    const int bm = (r2 / g.bnx) * 64, bn = (r2 % g.bnx) * 64;
    const unsigned short* A  = (const unsigned short*)g.A + (long)z * g.sA;
    const unsigned short* B  = (const unsigned short*)g.B + (long)z * g.sB;
    const unsigned short* Alp = (const unsigned short*)g.Al;
    const unsigned short* Blp = (const unsigned short*)g.Bl;

    const int wave = tid >> 6, lane = tid & 63;
    const int wm = (wave >> 1) * 32, wn = (wave & 1) * 32;
    const int lm = lane & 15, quad = lane >> 4;

    ffrag acc[2][2];
    #pragma unroll
    for (int mi = 0; mi < 2; ++mi)
        #pragma unroll
        for (int ni = 0; ni < 2; ++ni)
            #pragma unroll
            for (int r = 0; r < 4; ++r) acc[mi][ni][r] = 0.f;

    const int srow = tid >> 2, schunk = tid & 3;
    const long aoff = (long)(bm + srow) * g.lda + schunk * 8;
    int brow = bn + srow; if (brow > g.N - 1) brow = g.N - 1;
    const long boff = (long)brow * g.ldb + schunk * 8;
    const int loff = srow * 72 + schunk * 8;

    uint4 va0, va1, vb0, vb1, wa0, wa1, wb0, wb1;
    va0 = *(const uint4*)(A + aoff);
    va1 = *(const uint4*)(A + aoff + 32);
    vb0 = *(const uint4*)(B + boff);
    vb1 = *(const uint4*)(B + boff + 32);
    if (three) {
        wa0 = *(const uint4*)(Alp + aoff);
        wa1 = *(const uint4*)(Alp + aoff + 32);
        wb0 = *(const uint4*)(Blp + boff);
        wb1 = *(const uint4*)(Blp + boff + 32);
    }

    for (int k0 = 0; k0 < g.K; k0 += 64) {
        __syncthreads();
        *(uint4*)(Ahs + loff) = va0; *(uint4*)(Ahs + loff + 32) = va1;
        *(uint4*)(Bhs + loff) = vb0; *(uint4*)(Bhs + loff + 32) = vb1;
        if (three) {
            *(uint4*)(Als + loff) = wa0; *(uint4*)(Als + loff + 32) = wa1;
            *(uint4*)(Bls + loff) = wb0; *(uint4*)(Bls + loff + 32) = wb1;
        }
        __syncthreads();
        if (k0 + 64 < g.K) {
            va0 = *(const uint4*)(A + aoff + k0 + 64);
            va1 = *(const uint4*)(A + aoff + k0 + 96);
            vb0 = *(const uint4*)(B + boff + k0 + 64);
            vb1 = *(const uint4*)(B + boff + k0 + 96);
            if (three) {
                wa0 = *(const uint4*)(Alp + aoff + k0 + 64);
                wa1 = *(const uint4*)(Alp + aoff + k0 + 96);
                wb0 = *(const uint4*)(Blp + boff + k0 + 64);
                wb1 = *(const uint4*)(Blp + boff + k0 + 96);
            }
        }
        bfrag ah[2][2], bh[2][2], al[2][2], bl[2][2];
        #pragma unroll
        for (int mi = 0; mi < 2; ++mi)
            #pragma unroll
            for (int ks = 0; ks < 2; ++ks)
                ah[mi][ks] = *(const bfrag*)(Ahs + (wm + mi * 16 + lm) * 72 + ks * 32 + quad * 8);
        #pragma unroll
        for (int ni = 0; ni < 2; ++ni)
            #pragma unroll
            for (int ks = 0; ks < 2; ++ks)
                bh[ni][ks] = *(const bfrag*)(Bhs + (wn + ni * 16 + lm) * 72 + ks * 32 + quad * 8);
        if (three) {
            #pragma unroll
            for (int mi = 0; mi < 2; ++mi)
                #pragma unroll
                for (int ks = 0; ks < 2; ++ks)
                    al[mi][ks] = *(const bfrag*)(Als + (wm + mi * 16 + lm) * 72 + ks * 32 + quad * 8);
            #pragma unroll
            for (int ni = 0; ni < 2; ++ni)
                #pragma unroll
                for (int ks = 0; ks < 2; ++ks)
                    bl[ni][ks] = *(const bfrag*)(Bls + (wn + ni * 16 + lm) * 72 + ks * 32 + quad * 8);
        }
        #pragma unroll
        for (int mi = 0; mi < 2; ++mi)
            #pragma unroll
            for (int ni = 0; ni < 2; ++ni) {
                acc[mi][ni] = __builtin_amdgcn_mfma_f32_16x16x32_bf16(ah[mi][0], bh[ni][0], acc[mi][ni], 0, 0, 0);
                if (three) {
                    acc[mi][ni] = __builtin_amdgcn_mfma_f32_16x16x32_bf16(ah[mi][0], bl[ni][0], acc[mi][ni], 0, 0, 0);
                    acc[mi][ni] = __builtin_amdgcn_mfma_f32_16x16x32_bf16(al[mi][0], bh[ni][0], acc[mi][ni], 0, 0, 0);
                }
                acc[mi][ni] = __builtin_amdgcn_mfma_f32_16x16x32_bf16(ah[mi][1], bh[ni][1], acc[mi][ni], 0, 0, 0);
                if (three) {
                    acc[mi][ni] = __builtin_amdgcn_mfma_f32_16x16x32_bf16(ah[mi][1], bl[ni][1], acc[mi][ni], 0, 0, 0);
                    acc[mi][ni] = __builtin_amdgcn_mfma_f32_16x16x32_bf16(al[mi][1], bh[ni][1], acc[mi][ni], 0, 0, 0);
                }
            }
    }

    #pragma unroll
    for (int mi = 0; mi < 2; ++mi)
        #pragma unroll
        for (int ni = 0; ni < 2; ++ni) {
            int n = bn + wn + ni * 16 + lm;
            if (n < g.N) {
                int mb = bm + wm + mi * 16 + quad * 4;
                if (g.obf) {
                    unsigned short* C = (unsigned short*)g.C + (long)z * g.sC;
                    #pragma unroll
                    for (int r = 0; r < 4; ++r)
                        C[(long)(mb + r) * g.ldc + n] = f2bf(acc[mi][ni][r]);
                } else {
                    float* C = (float*)g.C + (long)z * g.sC;
                    #pragma unroll
                    for (int r = 0; r < 4; ++r)
                        C[(long)(mb + r) * g.ldc + n] = acc[mi][ni][r];
                }
            }
        }
}

// ---------------------------------------------------------------------------
// Merged transforms: blocks [0,4096) iq2, [4096,8192) ik2, [8192,9216) kv2.
// ---------------------------------------------------------------------------
__global__ __launch_bounds__(256) void mtrans_k(
    const float* __restrict__ iq, unsigned short* __restrict__ iqh, unsigned short* __restrict__ iql,
    const float* __restrict__ ik, unsigned short* __restrict__ ikh, unsigned short* __restrict__ ikl,
    const float* __restrict__ knw, const float* __restrict__ knb,
    const float* __restrict__ kva, unsigned short* __restrict__ kvb, const float* __restrict__ kvnw,
    const float* __restrict__ cosb, const float* __restrict__ sinb)
{
    __shared__ float red[256];
    __shared__ float rsh;
    const int b = blockIdx.x, tid = threadIdx.x;
    if (b < 8192) {
        const bool isq = b < 4096;
        int rb = isq ? b : b - 4096;
        int row = rb * 4 + (tid >> 6);
        int p = tid & 63;
        int t = row >> 4;
        const float* src = isq ? iq : ik;
        float a = src[(long)row * 128 + p];
        float bb = src[(long)row * 128 + 64 + p];
        if (!isq) {
            float ssum = a + bb;
            #pragma unroll
            for (int o = 1; o < 64; o <<= 1) ssum += __shfl_xor(ssum, o, 64);
            float m = ssum * (1.f / 128.f);
            float da = a - m, db = bb - m;
            float v = da * da + db * db;
            #pragma unroll
            for (int o = 1; o < 64; o <<= 1) v += __shfl_xor(v, o, 64);
            float r = rsqrtf(v * (1.f / 128.f) + 1e-5f);
            a = da * r * knw[p] + knb[p];
            bb = db * r * knw[64 + p] + knb[64 + p];
        }
        float c = cosb[t * 32 + (p & 31)], sn = sinb[t * 32 + (p & 31)];
        float asw = __shfl_xor(a, 32, 64);
        a = (p < 32) ? (a * c - asw * sn) : (asw * sn + a * c);
        #pragma unroll
        for (int h = 1; h < 64; h <<= 1) {
            float a2 = __shfl_xor(a, h, 64);
            float b2 = __shfl_xor(bb, h, 64);
            a = (p & h) ? (a2 - a) : (a + a2);
            bb = (p & h) ? (b2 - bb) : (bb + b2);
        }
        unsigned short* hi = isq ? iqh : ikh;
        unsigned short* lo = isq ? iql : ikl;
        unsigned short hb = f2bf(bb), ha = f2bf(a);
        hi[(long)row * 128 + p] = hb;
        hi[(long)row * 128 + 64 + p] = ha;
        lo[(long)row * 128 + p] = f2bf(bb - bf2f(hb));
        lo[(long)row * 128 + 64 + p] = f2bf(a - bf2f(ha));
    } else {
        int t = b - 8192;
        const float* a = kva + (long)t * CKV_;
        unsigned short* o = kvb + (long)t * CKV_;
        float v0 = a[tid], v1 = a[tid + 256];
        red[tid] = v0 * v0 + v1 * v1; __syncthreads();
        for (int off = 128; off; off >>= 1) { if (tid < off) red[tid] += red[tid + off]; __syncthreads(); }
        if (tid == 0) rsh = rsqrtf(red[0] / (float)KVLR_ + 1e-6f);
        __syncthreads();
        float rs = rsh;
        o[tid]       = f2bf(v0 * rs * kvnw[tid]);
        o[tid + 256] = f2bf(v1 * rs * kvnw[tid + 256]);
        if (tid < 32) {
            float x1 = a[512 + tid], x2 = a[544 + tid];
            float c = cosb[t * 32 + tid], sn = sinb[t * 32 + tid];
            o[512 + tid] = f2bf(x1 * c - x2 * sn);
            o[544 + tid] = f2bf(x1 * sn + x2 * c);
        }
    }
}

// ---------------------------------------------------------------------------
// Indexer score (MFMA bf16x3), BK=64, SPLIT 4-WAY OVER HEADS (blockIdx.z):
// z handles heads [z*4, z*4+4), writing a partial score to
// scorep + z*T*T. 544 active blocks (vs 136) -> ~2 blocks/CU of TLP and
// 1/4 the per-block serial latency chain. topk sums the 4 partials.
// ---------------------------------------------------------------------------
__global__ __launch_bounds__(256) void score3_k(
    const unsigned short* __restrict__ iqh, const unsigned short* __restrict__ iql,
    const unsigned short* __restrict__ ikh, const unsigned short* __restrict__ ikl,
    const float* __restrict__ wtok, float* __restrict__ scorep)
{
    const int bt = blockIdx.y, bs = blockIdx.x;
    if (bs > bt) return;
    const int hz = blockIdx.z;           // 0..3, heads [hz*4, hz*4+4)
    const int h0 = hz * 4;
    float* score = scorep + (long)hz * (T_ * T_);
    __shared__ unsigned short Ah[64 * 72], Al[64 * 72], Bh[64 * 72], Bl[64 * 72];
    __shared__ float wts[64][16];
    const int tid = threadIdx.x;
    const int wave = tid >> 6, lane = tid & 63;
    const int wm = (wave >> 1) * 32, wn = (wave & 1) * 32;
    const int lm = lane & 15, quad = lane >> 4;
    const int t0 = bt * 64, s0 = bs * 64;
    const int srow = tid >> 2, schunk = tid & 3;
    const int loff = srow * 72 + schunk * 8;

    for (int e = tid; e < 1024; e += 256)
        wts[e >> 4][e & 15] = wtok[(long)(t0 + (e >> 4)) * IH_ + (e & 15)];

    const long abase = (long)(t0 + srow) * 2048 + schunk * 8 + h0 * 128;
    const long bbase = (long)(s0 + srow) * 2048 + schunk * 8 + h0 * 128;

    uint4 pah0 = *(const uint4*)(iqh + abase);
    uint4 pah1 = *(const uint4*)(iqh + abase + 32);
    uint4 pal0 = *(const uint4*)(iql + abase);
    uint4 pal1 = *(const uint4*)(iql + abase + 32);
    uint4 pbh0 = *(const uint4*)(ikh + bbase);
    uint4 pbh1 = *(const uint4*)(ikh + bbase + 32);
    uint4 pbl0 = *(const uint4*)(ikl + bbase);
    uint4 pbl1 = *(const uint4*)(ikl + bbase + 32);

    float accf[2][2][4] = {};

    for (int hh = 0; hh < 4; ++hh) {
        const int h = h0 + hh;
        ffrag acch[2][2];
        #pragma unroll
        for (int mi = 0; mi < 2; ++mi)
            #pragma unroll
            for (int ni = 0; ni < 2; ++ni)
                #pragma unroll
                for (int r = 0; r < 4; ++r) acch[mi][ni][r] = 0.f;

        #pragma unroll
        for (int k0 = 0; k0 < ID_; k0 += 64) {
            __syncthreads();
            *(uint4*)(Ah + loff) = pah0; *(uint4*)(Ah + loff + 32) = pah1;
            *(uint4*)(Al + loff) = pal0; *(uint4*)(Al + loff + 32) = pal1;
            *(uint4*)(Bh + loff) = pbh0; *(uint4*)(Bh + loff + 32) = pbh1;
            *(uint4*)(Bl + loff) = pbl0; *(uint4*)(Bl + loff + 32) = pbl1;
            __syncthreads();
            int step = hh * 2 + (k0 >> 6) + 1;
            if (step < 8) {
                long off = (long)(step >> 1) * 128 + (step & 1) * 64;
                pah0 = *(const uint4*)(iqh + abase + off);
                pah1 = *(const uint4*)(iqh + abase + off + 32);
                pal0 = *(const uint4*)(iql + abase + off);
                pal1 = *(const uint4*)(iql + abase + off + 32);
                pbh0 = *(const uint4*)(ikh + bbase + off);
                pbh1 = *(const uint4*)(ikh + bbase + off + 32);
                pbl0 = *(const uint4*)(ikl + bbase + off);
                pbl1 = *(const uint4*)(ikl + bbase + off + 32);
            }
            bfrag ahf[2][2], alf[2][2], bhf[2][2], blf[2][2];
            #pragma unroll
            for (int mi = 0; mi < 2; ++mi)
                #pragma unroll
                for (int ks = 0; ks < 2; ++ks) {
                    ahf[mi][ks] = *(const bfrag*)(Ah + (wm + mi * 16 + lm) * 72 + ks * 32 + quad * 8);
                    alf[mi][ks] = *(const bfrag*)(Al + (wm + mi * 16 + lm) * 72 + ks * 32 + quad * 8);
                }
            #pragma unroll
            for (int ni = 0; ni < 2; ++ni)
                #pragma unroll
                for (int ks = 0; ks < 2; ++ks) {
                    bhf[ni][ks] = *(const bfrag*)(Bh + (wn + ni * 16 + lm) * 72 + ks * 32 + quad * 8);
                    blf[ni][ks] = *(const bfrag*)(Bl + (wn + ni * 16 + lm) * 72 + ks * 32 + quad * 8);
                }
            #pragma unroll
            for (int mi = 0; mi < 2; ++mi)
                #pragma unroll
                for (int ni = 0; ni < 2; ++ni) {
                    acch[mi][ni] = __builtin_amdgcn_mfma_f32_16x16x32_bf16(ahf[mi][0], bhf[ni][0], acch[mi][ni], 0, 0, 0);
                    acch[mi][ni] = __builtin_amdgcn_mfma_f32_16x16x32_bf16(ahf[mi][0], blf[ni][0], acch[mi][ni], 0, 0, 0);
                    acch[mi][ni] = __builtin_amdgcn_mfma_f32_16x16x32_bf16(alf[mi][0], bhf[ni][0], acch[mi][ni], 0, 0, 0);
                    acch[mi][ni] = __builtin_amdgcn_mfma_f32_16x16x32_bf16(ahf[mi][1], bhf[ni][1], acch[mi][ni], 0, 0, 0);
                    acch[mi][ni] = __builtin_amdgcn_mfma_f32_16x16x32_bf16(ahf[mi][1], blf[ni][1], acch[mi][ni], 0, 0, 0);
                    acch[mi][ni] = __builtin_amdgcn_mfma_f32_16x16x32_bf16(alf[mi][1], bhf[ni][1], acch[mi][ni], 0, 0, 0);
                }
        }
        #pragma unroll
        for (int mi = 0; mi < 2; ++mi) {
            float wr[4];
            #pragma unroll
            for (int r = 0; r < 4; ++r) wr[r] = wts[wm + mi * 16 + quad * 4 + r][h];
            #pragma unroll
            for (int ni = 0; ni < 2; ++ni)
                #pragma unroll
                for (int r = 0; r < 4; ++r)
                    accf[mi][ni][r] += fmaxf(acch[mi][ni][r], 0.f) * wr[r];
        }
    }
    #pragma unroll
    for (int mi = 0; mi < 2; ++mi)
        #pragma unroll
        for (int ni = 0; ni < 2; ++ni) {
            int s = s0 + wn + ni * 16 + lm;
            int tb = t0 + wm + mi * 16 + quad * 4;
            #pragma unroll
            for (int r = 0; r < 4; ++r)
                score[(long)(tb + r) * T_ + s] = accf[mi][ni][r];
        }
}

// ---------------------------------------------------------------------------
// Top-256 per row via bitonic sort; sums the 4 head-group score partials.
// ---------------------------------------------------------------------------
__global__ __launch_bounds__(512) void topk_k(const float* __restrict__ scorep, int* __restrict__ topk)
{
    int t = blockIdx.x, tid = threadIdx.x;
    __shared__ float v[1024];
    __shared__ int ix[1024];
    const float* p0 = scorep + (long)t * T_;
    const float* p1 = p0 + (long)1 * T_ * T_;
    const float* p2 = p0 + (long)2 * T_ * T_;
    const float* p3 = p0 + (long)3 * T_ * T_;
    for (int i = tid; i < 1024; i += 512) {
        v[i] = (i <= t) ? (p0[i] + p1[i] + p2[i] + p3[i]) : -INFINITY;
        ix[i] = i;
    }
    __syncthreads();
    for (int k = 2; k <= 1024; k <<= 1) {
        for (int j = k >> 1; j > 0; j >>= 1) {
            for (int i = tid; i < 1024; i += 512) {
                int l = i ^ j;
                if (l > i) {
                    bool up = ((i & k) == 0);
                    float vi = v[i], vl = v[l];
                    int xi = ix[i], xl = ix[l];
                    bool iBetter = (vi > vl) || (vi == vl && xi < xl);
                    bool doSwap = up ? !iBetter : iBetter;
                    if (doSwap) { v[i] = vl; v[l] = vi; ix[i] = xl; ix[l] = xi; }
                }
            }
            __syncthreads();
        }
    }
    if (tid < 256) topk[(long)t * TOPK_ + tid] = ix[tid];
}

// ---------------------------------------------------------------------------
// Attention v7b (MFMA bf16): bf16 Q input; phase A depth-3 reg ring,
// phase B dbuf VT + raw barriers. Unchanged (parked at ~75 us).
// ---------------------------------------------------------------------------
__global__ __launch_bounds__(256, 4) void attn3_k(
    const unsigned short* __restrict__ qkeyb, const unsigned short* __restrict__ kvb,
    const int* __restrict__ topkp, unsigned short* __restrict__ olat)
{
    __shared__ __align__(16) unsigned short U[13568];
    __shared__ float red[16 * 17];
    __shared__ int kidx[256];
    unsigned short* Qbf = U;                    // [16][584] (phase A)
    float*          Lg  = (float*)U;            // [16][260] (after phase A)
    unsigned short* VT0 = U;                    // [128][36] (phase B buf 0)
    unsigned short* VT1 = U + 4608;             // [128][36] (phase B buf 1)
    unsigned short* Pbf = U + 9344;             // [16][264]

    const int t = blockIdx.x, tid = threadIdx.x;
    const int wave = tid >> 6, lane = tid & 63;
    const int lm = lane & 15, quad = lane >> 4;

    kidx[tid] = topkp[(long)t * TOPK_ + tid];
    const uint2* q2 = (const uint2*)(qkeyb + (long)t * (H_ * CKV_));
    #pragma unroll
    for (int rep = 0; rep < 9; ++rep) {
        int e = rep * 256 + tid;
        uint2 v = q2[e];
        int f = e * 4, h = f / CKV_, c = f - h * CKV_;
        *(uint2*)(Qbf + h * 584 + c) = v;
    }
    int myk0 = topkp[(long)t * TOPK_ + wave * 64 + 0 * 16 + lm];
    int myk1 = topkp[(long)t * TOPK_ + wave * 64 + 1 * 16 + lm];
    int myk2 = topkp[(long)t * TOPK_ + wave * 64 + 2 * 16 + lm];
    int myk3 = topkp[(long)t * TOPK_ + wave * 64 + 3 * 16 + lm];
    __syncthreads();

    ffrag acc[4];
    #pragma unroll
    for (int ni = 0; ni < 4; ++ni)
        #pragma unroll
        for (int r = 0; r < 4; ++r) acc[ni][r] = 0.f;

    const unsigned short* kb0 = kvb + (long)myk0 * CKV_ + quad * 8;
    const unsigned short* kb1 = kvb + (long)myk1 * CKV_ + quad * 8;
    const unsigned short* kb2 = kvb + (long)myk2 * CKV_ + quad * 8;
    const unsigned short* kb3 = kvb + (long)myk3 * CKV_ + quad * 8;

    bfrag ba[4], bb[4], bc[4];
    #define LDT(DST, C) { \
        DST[0] = *(const bfrag*)(kb0 + (C)); \
        DST[1] = *(const bfrag*)(kb1 + (C)); \
        DST[2] = *(const bfrag*)(kb2 + (C)); \
        DST[3] = *(const bfrag*)(kb3 + (C)); }
    #define PHA_STEP(I, BUF) { \
        bfrag af = *(const bfrag*)(Qbf + lm * 584 + (I) * 32 + quad * 8); \
        _Pragma("unroll") \
        for (int ni = 0; ni < 4; ++ni) \
            acc[ni] = __builtin_amdgcn_mfma_f32_16x16x32_bf16(af, BUF[ni], acc[ni], 0, 0, 0); \
        if ((I) < 15) LDT(BUF, (I) * 32 + 96) }

    LDT(ba, 0) LDT(bb, 32) LDT(bc, 64)
    PHA_STEP(0, ba)  PHA_STEP(1, bb)  PHA_STEP(2, bc)
    PHA_STEP(3, ba)  PHA_STEP(4, bb)  PHA_STEP(5, bc)
    PHA_STEP(6, ba)  PHA_STEP(7, bb)  PHA_STEP(8, bc)
    PHA_STEP(9, ba)  PHA_STEP(10, bb) PHA_STEP(11, bc)
    PHA_STEP(12, ba) PHA_STEP(13, bb) PHA_STEP(14, bc)
    PHA_STEP(15, ba) PHA_STEP(16, bb) PHA_STEP(17, bc)
    #undef PHA_STEP
    #undef LDT

    __syncthreads();
    #pragma unroll
    for (int ni = 0; ni < 4; ++ni)
        #pragma unroll
        for (int r = 0; r < 4; ++r)
            Lg[(quad * 4 + r) * 260 + wave * 64 + ni * 16 + lm] = acc[ni][r];
    __syncthreads();

    {
        int h = tid >> 4, j = tid & 15;
        float m = -INFINITY;
        #pragma unroll
        for (int kk = 0; kk < 16; ++kk) {
            int key = j * 16 + kk;
            if (kidx[key] <= t) m = fmaxf(m, Lg[h * 260 + key]);
        }
        red[h * 17 + j] = m;
        __syncthreads();
        float mh = -INFINITY;
        #pragma unroll
        for (int jj = 0; jj < 16; ++jj) mh = fmaxf(mh, red[h * 17 + jj]);
        __syncthreads();
        float s = 0.f;
        float pv[16];
        #pragma unroll
        for (int kk = 0; kk < 16; ++kk) {
            int key = j * 16 + kk;
            float e = (kidx[key] <= t) ? expf(Lg[h * 260 + key] * SCALE_LOG - mh * SCALE_LOG) : 0.f;
            pv[kk] = e; s += e;
        }
        red[h * 17 + j] = s;
        __syncthreads();
        float sh = 0.f;
        #pragma unroll
        for (int jj = 0; jj < 16; ++jj) sh += red[h * 17 + jj];
        float inv = 1.f / sh;
        #pragma unroll
        for (int kk = 0; kk < 16; ++kk)
            Pbf[h * 264 + j * 16 + kk] = f2bf(pv[kk] * inv);
    }

    const int kpair = tid & 15, cgrp = tid >> 4;
    ffrag acc2[2];
    #pragma unroll
    for (int ci = 0; ci < 2; ++ci)
        #pragma unroll
        for (int r = 0; r < 4; ++r) acc2[ci][r] = 0.f;

    uint4 ga0, gb0, ga1, gb1;
    #define PREFB(GA, GB, IT) { \
        int ka_ = kidx[((IT) & 7) * 32 + 2 * kpair]; \
        int kb_ = kidx[((IT) & 7) * 32 + 2 * kpair + 1]; \
        long co_ = (long)(((IT) >> 3) * 128 + cgrp * 8); \
        GA = *(const uint4*)(kvb + (long)ka_ * CKV_ + co_); \
        GB = *(const uint4*)(kvb + (long)kb_ * CKV_ + co_); }
    #define STOREB(GA, GB, BUF) { \
        const unsigned short* pa_ = (const unsigned short*)&GA; \
        const unsigned short* pb_ = (const unsigned short*)&GB; \
        _Pragma("unroll") \
        for (int i_ = 0; i_ < 8; ++i_) \
            *(unsigned int*)((BUF) + (cgrp * 8 + i_) * 36 + 2 * kpair) = \
                (unsigned int)pa_[i_] | ((unsigned int)pb_[i_] << 16); }
    #define MFMAB(BUF, IT) { \
        bfrag pa = *(const bfrag*)(Pbf + lm * 264 + ((IT) & 7) * 32 + quad * 8); \
        _Pragma("unroll") \
        for (int ci = 0; ci < 2; ++ci) { \
            int c = wave * 32 + ci * 16 + lm; \
            bfrag bv; \
            ((uint2*)&bv)[0] = *(const uint2*)((BUF) + c * 36 + quad * 8); \
            ((uint2*)&bv)[1] = *(const uint2*)((BUF) + c * 36 + quad * 8 + 4); \
            acc2[ci] = __builtin_amdgcn_mfma_f32_16x16x32_bf16(pa, bv, acc2[ci], 0, 0, 0); } }
    #define OLATST(IT) { \
        int p_ = (IT) >> 3; \
        _Pragma("unroll") \
        for (int ci = 0; ci < 2; ++ci) \
            _Pragma("unroll") \
            for (int r = 0; r < 4; ++r) \
                olat[((long)t * H_ + quad * 4 + r) * 512 + p_ * 128 + wave * 32 + ci * 16 + lm] \
                    = f2bf(acc2[ci][r]); \
        _Pragma("unroll") \
        for (int ci = 0; ci < 2; ++ci) \
            _Pragma("unroll") \
            for (int r = 0; r < 4; ++r) acc2[ci][r] = 0.f; }
    #define LGKBAR() { asm volatile("s_waitcnt lgkmcnt(0)" ::: "memory"); \
                       __builtin_amdgcn_s_barrier(); }

    PREFB(ga0, gb0, 0);
    PREFB(ga1, gb1, 1);
    LGKBAR();
    STOREB(ga0, gb0, VT0);
    LGKBAR();
    for (int it = 0; it < 32; it += 2) {
        STOREB(ga1, gb1, VT1);
        MFMAB(VT0, it);
        if (it + 2 < 32) PREFB(ga0, gb0, it + 2);
        LGKBAR();
        if (it + 2 < 32) STOREB(ga0, gb0, VT0);
        MFMAB(VT1, it + 1);
        if (it + 3 < 32) PREFB(ga1, gb1, it + 3);
        if (((it + 1) & 7) == 7) OLATST(it + 1);
        LGKBAR();
    }
    #undef PREFB
    #undef STOREB
    #undef MFMAB
    #undef OLATST
    #undef LGKBAR
}

// ---------------------------------------------------------------------------
extern "C" void kernel_launch(void* const* d_in, const int* in_sizes, int n_in,
                              void* d_out, int out_size, void* d_ws, size_t ws_size,
                              hipStream_t stream)
{
    const float* x          = (const float*)d_in[0];
    const float* cosb       = (const float*)d_in[1];
    const float* sinb       = (const float*)d_in[2];
    const float* wq_a       = (const float*)d_in[3];
    const float* q_norm_w   = (const float*)d_in[4];
    const float* wq_b       = (const float*)d_in[5];
    const float* wkv_a      = (const float*)d_in[6];
    const float* kv_norm_w  = (const float*)d_in[7];
    const float* wkv_b      = (const float*)d_in[8];
    const float* wo         = (const float*)d_in[9];
    const float* iq_norm_w  = (const float*)d_in[10];
    const float* iwq_b      = (const float*)d_in[11];
    const float* iwk        = (const float*)d_in[12];
    const float* k_norm_w   = (const float*)d_in[13];
    const float* k_norm_b   = (const float*)d_in[14];
    const float* wproj      = (const float*)d_in[15];
    float* out = (float*)d_out;

    // fp32 workspace (float offsets)
    float* ws    = (float*)d_ws;
    float* qr    = ws;                      // 1,048,576 (dead after qrnorm -> kvb slot)
    float* wtok  = ws + 1049600;
    int*   topk  = (int*)(ws + 1655808);    // 262,144 ints
    float* qkey  = ws + 1917952;            // 9,437,184 floats (bf16 sublayout region)
    float* outv  = ws + 11355136;           // 2,097,152 (slot)
    float* U0    = ws + 13452288;           // union region
    float* iq    = U0;                      // 2,097,152
    float* ik    = U0 + 2097152;            // 2,097,152
    float* kva   = U0 + 4194304;            // 589,824
    float* qbuf  = U0 + 4784128;            // 3,145,728
    // score partials (4 x 1,048,576 floats) live in the iq+ik slots, which
    // are dead after mtrans consumes them and before step-9 writes qbf/wkT.
    float* scorep = U0;                     // 4,194,304 floats

    // bf16 sublayouts (ushort units) in the qkey region
    unsigned short* qkey_u = (unsigned short*)qkey;
    unsigned short* wqa_hi  = qkey_u;
    unsigned short* wqa_lo  = qkey_u + 2097152;
    unsigned short* iwk_hi  = qkey_u + 4194304;
    unsigned short* iwk_lo  = qkey_u + 8388608;
    unsigned short* iwqb_hi = qkey_u + 12582912;
    unsigned short* iwqb_lo = qkey_u + 14680064;
    unsigned short* qriq_hi = qkey_u + 16777216;
    unsigned short* qriq_lo = qkey_u + 17825792;
    unsigned short* iqbf_hi = qkey_u;
    unsigned short* iqbf_lo = qkey_u + 2097152;
    unsigned short* ikbf_hi = qkey_u + 4194304;
    unsigned short* ikbf_lo = qkey_u + 6291456;
    unsigned short* qkey_bf = qkey_u;                    // 9,437,184 ushorts
    unsigned short* wkvb_bf = qkey_u + 9437184;          // 2,097,152 (over dead iwk_lo)
    unsigned short* wo_bf   = qkey_u;                    // qkey region dead after attn3
    unsigned short* q_u     = (unsigned short*)qbuf;
    unsigned short* x_hi    = q_u;
    unsigned short* x_lo    = q_u + 2097152;
    unsigned short* wkva_hi = q_u + 4194304;
    unsigned short* outv_u  = (unsigned short*)outv;
    unsigned short* wqb_hi  = outv_u;
    unsigned short* qrq_hi  = outv_u + 3145728;
    unsigned short* outv_bf = outv_u;
    unsigned short* qbf     = (unsigned short*)iq;
    unsigned short* wkT     = (unsigned short*)ik;
    unsigned short* kvb     = (unsigned short*)qr;
    unsigned short* olat_bf = (unsigned short*)U0;

    // ---- 1. mega-cast 1 ----
    {
        CastDesc d;
        d.seg[0] = { x,      x_hi,    x_lo    };
        d.seg[1] = { wq_a,   wqa_hi,  wqa_lo  };
        d.seg[2] = { iwk,    iwk_hi,  iwk_lo  };
        d.seg[3] = { iwq_b,  iwqb_hi, iwqb_lo };
        d.seg[4] = { wkv_a,  wkva_hi, nullptr };
        d.seg[5] = { wq_b,   wqb_hi,  nullptr };
        d.bstart[0] = 0;     d.bstart[1] = 2048;  d.bstart[2] = 4096;
        d.bstart[3] = 8192;  d.bstart[4] = 10240; d.bstart[5] = 11392;
        d.bstart[6] = 14464; d.nseg = 6;
        castm_k<<<14464, 256, 0, stream>>>(d);
    }

    // ---- 2. Launch A: qr(bf16x3) + ik(bf16x3) + wtok ----
    {
        GDesc d{};
        d.nseg = 3;
        d.bstart[0] = 0; d.bstart[1] = 256; d.bstart[2] = 768; d.bstart[3] = 1792;
        GSeg& s0 = d.seg[0];
        s0.A = x_hi; s0.Al = x_lo; s0.B = wqa_hi; s0.Bl = wqa_lo; s0.C = qr;
        s0.lda = DIM_; s0.ldb = DIM_; s0.ldc = QLR_; s0.N = QLR_; s0.K = DIM_;
        s0.bnx = 16; s0.bmx = 16; s0.mode = 1; s0.obf = 0;
        GSeg& s1 = d.seg[1];
        s1.A = x_hi; s1.Al = x_lo; s1.B = iwk_hi; s1.Bl = iwk_lo; s1.C = ik;
        s1.lda = DIM_; s1.ldb = DIM_; s1.ldc = IH_ * ID_; s1.N = IH_ * ID_; s1.K = DIM_;
        s1.bnx = 32; s1.bmx = 16; s1.mode = 1; s1.obf = 0;
        GSeg& s2 = d.seg[2];
        s2.A = x; s2.B = wproj; s2.C = wtok; s2.mode = 3;
        mgemm_k<<<1792, 256, 0, stream>>>(d);
    }

    // ---- 3. fused rstd + qriq(hi/lo) + qrq(hi) ----
    qrnorm_k<<<T_, 256, 0, stream>>>(qr, iq_norm_w, q_norm_w, qriq_hi, qriq_lo, qrq_hi);

    // ---- 4. Launch B1: iq(bf16x3) + kva(bf16) + wkv_b cast ----
    {
        GDesc d{};
        d.nseg = 3;
        d.bstart[0] = 0; d.bstart[1] = 512; d.bstart[2] = 656; d.bstart[3] = 2704;
        GSeg& s0 = d.seg[0];
        s0.A = qriq_hi; s0.Al = qriq_lo; s0.B = iwqb_hi; s0.Bl = iwqb_lo; s0.C = iq;
        s0.lda = QLR_; s0.ldb = QLR_; s0.ldc = IH_ * ID_; s0.N = IH_ * ID_; s0.K = QLR_;
        s0.bnx = 32; s0.bmx = 16; s0.mode = 1; s0.obf = 0;
        GSeg& s1 = d.seg[1];
        s1.A = x_hi; s1.B = wkva_hi; s1.C = kva;
        s1.lda = DIM_; s1.ldb = DIM_; s1.ldc = CKV_; s1.N = CKV_; s1.K = DIM_;
        s1.bnx = 9; s1.bmx = 16; s1.mode = 0; s1.obf = 0;
        GSeg& s2 = d.seg[2];
        s2.A = wkv_b; s2.C = wkvb_bf; s2.C2 = nullptr; s2.mode = 2;   // 2048 blocks
        mgemm_k<<<2704, 256, 0, stream>>>(d);
    }

    // ---- 5. Launch B2: q = rmsnorm(qr,q_norm) @ wq_b.T ----
    {
        GDesc d{};
        d.nseg = 1;
        d.bstart[0] = 0; d.bstart[1] = 768;
        GSeg& s0 = d.seg[0];
        s0.A = qrq_hi; s0.B = wqb_hi; s0.C = qbuf;
        s0.lda = QLR_; s0.ldb = QLR_; s0.ldc = H_ * QKD_; s0.N = H_ * QKD_; s0.K = QLR_;
        s0.bnx = 48; s0.bmx = 16; s0.mode = 0; s0.obf = 0;
        mgemm_k<<<768, 256, 0, stream>>>(d);
    }

    // ---- 6. merged transforms ----
    mtrans_k<<<9216, 256, 0, stream>>>(iq, iqbf_hi, iqbf_lo, ik, ikbf_hi, ikbf_lo,
                                       k_norm_w, k_norm_b, kva, kvb, kv_norm_w, cosb, sinb);

    // ---- 7/8. score (4-way head split into scorep) + topk (sums partials) ----
    score3_k<<<dim3(T_/64, T_/64, 4), 256, 0, stream>>>(iqbf_hi, iqbf_lo, ikbf_hi, ikbf_lo, wtok, scorep);
    topk_k<<<T_, 512, 0, stream>>>(scorep, topk);

    // ---- 9. qbuf cast + tcast + qpe (one launch) ----
    {
        GDesc d{};
        d.nseg = 3;
        d.bstart[0] = 0; d.bstart[1] = 3072; d.bstart[2] = 4096; d.bstart[3] = 6144;
        GSeg& s0 = d.seg[0];
        s0.A = qbuf; s0.C = qbf; s0.C2 = nullptr; s0.mode = 2;      // 3072 blocks
        GSeg& s1 = d.seg[1];
        s1.A = wkv_b; s1.C = wkT; s1.mode = 4;                      // 1024 blocks
        GSeg& s2 = d.seg[2];
        s2.A = qbuf; s2.B = cosb; s2.Bl = sinb; s2.C = qkey_bf; s2.mode = 5;  // 2048 blocks
        mgemm_k<<<6144, 256, 0, stream>>>(d);
    }

    // ---- 10. q_nope_proj (128^2 batched) ----
    gemm_bt_mfma_k<<<dim3(KVLR_/128, T_/128, H_), 256, 0, stream>>>(
        qbf, wkT, qkey_bf, 192L, 65536L, 576L, H_*QKD_, ID_, H_*CKV_, KVLR_, ID_, 1);

    // ---- 11. attention -> olat bf16 @ U0 ----
    attn3_k<<<T_, 256, 0, stream>>>(qkey_bf, kvb, topk, olat_bf);

    // ---- 12. Launch D: outv GEMM (batched, bf16 out) + wo cast ----
    {
        GDesc d{};
        d.nseg = 2;
        d.bstart[0] = 0; d.bstart[1] = 512; d.bstart[2] = 4608;
        GSeg& s0 = d.seg[0];
        s0.A = olat_bf; s0.B = wkvb_bf + (long)NOPE_ * KVLR_; s0.C = outv_bf;
        s0.sA = 512; s0.sB = (long)(NOPE_ + VD_) * KVLR_; s0.sC = VD_;
        s0.lda = H_ * KVLR_; s0.ldb = KVLR_; s0.ldc = H_ * VD_; s0.N = VD_; s0.K = KVLR_;
        s0.bnx = 2; s0.bmx = 16; s0.mode = 0; s0.obf = 1;
        GSeg& s1 = d.seg[1];
        s1.A = wo; s1.C = wo_bf; s1.C2 = nullptr; s1.mode = 2;      // 4096 blocks
        mgemm_k<<<4608, 256, 0, stream>>>(d);
    }

    // ---- 13. out = outv @ wo.T ----
    {
        GDesc d{};
        d.nseg = 1;
        d.bstart[0] = 0; d.bstart[1] = 512;
        GSeg& s0 = d.seg[0];
        s0.A = outv_bf; s0.B = wo_bf; s0.C = out;
        s0.lda = H_ * VD_; s0.ldb = H_ * VD_; s0.ldc = DIM_; s0.N = DIM_; s0.K = H_ * VD_;
        s0.bnx = 32; s0.bmx = 16; s0.mode = 0; s0.obf = 0;
        mgemm_k<<<512, 256, 0, stream>>>(d);
    }

    (void)in_sizes; (void)n_in; (void)out_size; (void)ws_size;
}